// Round 1
// baseline (1432.828 us; speedup 1.0000x reference)
//
#include <hip/hip_runtime.h>
#include <math.h>

#define DM   512
#define HH   8
#define HDD  64
#define ETA_ 4
#define RR   8
#define TT   128
#define BBATCH 32
#define MM   (TT*BBATCH)     // 4096 rows
#define NPROJ 2656
#define KQV  2560

__device__ __forceinline__ float sigmoidf_(float x) {
    return 1.0f / (1.0f + __expf(-x));
}

// ---------------- LayerNorm (one row of 512 per block, 256 threads) -------
__global__ __launch_bounds__(256) void ln_kernel(const float* __restrict__ x,
    const float* __restrict__ g, const float* __restrict__ b,
    float* __restrict__ out)
{
    int row = blockIdx.x;
    int tid = threadIdx.x;
    const float* xr = x + (size_t)row * DM;
    float2 v = ((const float2*)xr)[tid];
    float s = v.x + v.y;
    #pragma unroll
    for (int off = 32; off; off >>= 1) s += __shfl_down(s, off);
    __shared__ float red[8];
    int wid = tid >> 6, lane = tid & 63;
    if (lane == 0) red[wid] = s;
    __syncthreads();
    if (tid == 0) red[0] = (red[0] + red[1] + red[2] + red[3]) * (1.0f / DM);
    __syncthreads();
    float mean = red[0];
    float dx = v.x - mean, dy = v.y - mean;
    float sq = dx*dx + dy*dy;
    #pragma unroll
    for (int off = 32; off; off >>= 1) sq += __shfl_down(sq, off);
    if (lane == 0) red[4 + wid] = sq;
    __syncthreads();
    if (tid == 0) red[1] = rsqrtf((red[4]+red[5]+red[6]+red[7]) * (1.0f/DM) + 1e-5f);
    __syncthreads();
    float rstd = red[1];
    float2 gg = ((const float2*)g)[tid];
    float2 bb = ((const float2*)b)[tid];
    float2 o;
    o.x = dx * rstd * gg.x + bb.x;
    o.y = dy * rstd * gg.y + bb.y;
    ((float2*)(out + (size_t)row * DM))[tid] = o;
}

// ---------------- f32 tiled GEMM: C[M,N] = act(A[M,K] @ W[N,K]^T + bias) --
// A row-major MxK, W row-major NxK. M multiple of 64; N,K arbitrary mult of 16.
#define BM 64
#define BN 64
#define BK 16

__global__ __launch_bounds__(256) void gemm_tn(const float* __restrict__ A,
    const float* __restrict__ W, const float* __restrict__ bias,
    float* __restrict__ C, int M, int N, int K, int act)
{
    __shared__ float As[BK][BM + 4];
    __shared__ float Ws[BK][BN + 4];
    int tid = threadIdx.x;
    int m0 = blockIdx.y * BM, n0 = blockIdx.x * BN;
    int lr = tid >> 2;             // 0..63: tile row
    int lk = (tid & 3) << 2;       // 0,4,8,12: k offset (float4)
    int tx = tid & 15, ty = tid >> 4;
    float acc[4][4] = {};
    for (int k0 = 0; k0 < K; k0 += BK) {
        float4 a4 = *(const float4*)(A + (size_t)(m0 + lr) * K + k0 + lk);
        float4 w4 = make_float4(0.f, 0.f, 0.f, 0.f);
        int wr = n0 + lr;
        if (wr < N) w4 = *(const float4*)(W + (size_t)wr * K + k0 + lk);
        __syncthreads();
        As[lk+0][lr] = a4.x; As[lk+1][lr] = a4.y; As[lk+2][lr] = a4.z; As[lk+3][lr] = a4.w;
        Ws[lk+0][lr] = w4.x; Ws[lk+1][lr] = w4.y; Ws[lk+2][lr] = w4.z; Ws[lk+3][lr] = w4.w;
        __syncthreads();
        #pragma unroll
        for (int k = 0; k < BK; ++k) {
            float a0 = As[k][ty*4+0], a1 = As[k][ty*4+1];
            float a2 = As[k][ty*4+2], a3 = As[k][ty*4+3];
            float b0 = Ws[k][tx*4+0], b1 = Ws[k][tx*4+1];
            float b2 = Ws[k][tx*4+2], b3 = Ws[k][tx*4+3];
            acc[0][0] += a0*b0; acc[0][1] += a0*b1; acc[0][2] += a0*b2; acc[0][3] += a0*b3;
            acc[1][0] += a1*b0; acc[1][1] += a1*b1; acc[1][2] += a1*b2; acc[1][3] += a1*b3;
            acc[2][0] += a2*b0; acc[2][1] += a2*b1; acc[2][2] += a2*b2; acc[2][3] += a2*b3;
            acc[3][0] += a3*b0; acc[3][1] += a3*b1; acc[3][2] += a3*b2; acc[3][3] += a3*b3;
        }
    }
    #pragma unroll
    for (int i = 0; i < 4; ++i) {
        int m = m0 + ty*4 + i;
        #pragma unroll
        for (int j = 0; j < 4; ++j) {
            int n = n0 + tx*4 + j;
            if (n < N) {
                float v = acc[i][j];
                if (bias) v += bias[n];
                if (act) v = fmaxf(v, 0.f);
                C[(size_t)m * N + n] = v;
            }
        }
    }
}

// ---------------- fused prepare + discounted scans + attention ------------
// One block per (b,h): B*H = 256 blocks, 256 threads.
// Thread tid owns: final_s[e=tid], final_keys[r=0..7][e=tid],
//                  final_values at (r0,d0) and (r0+4,d0), r0=tid>>6, d0=tid&63.
__global__ __launch_bounds__(256) void scan_attn_kernel(
    const float* __restrict__ proj, const int* __restrict__ term,
    const float* __restrict__ tick, const float* __restrict__ tilde_k,
    const float* __restrict__ tilde_v, const float* __restrict__ s_prev,
    float* __restrict__ attn)
{
    int b = blockIdx.x >> 3;
    int h = blockIdx.x & 7;
    int tid = threadIdx.x;
    int d_e = tid >> 2, p_e = tid & 3;     // keys_exp index j = d*ETA + p
    int r0 = tid >> 6, d0 = tid & 63;

    float fs = s_prev[((size_t)b*HH + h)*256 + tid];
    float fk[8];
    #pragma unroll
    for (int r = 0; r < 8; ++r)
        fk[r] = tilde_k[(((size_t)b*RR + r)*HH + h)*256 + tid];
    float fv0 = tilde_v[(((size_t)b*RR + r0)*HH + h)*64 + d0];
    float fv1 = tilde_v[(((size_t)b*RR + r0 + 4)*HH + h)*64 + d0];
    float tickb = tick[b];

    __shared__ float sp[332];     // 0..319: kqvbg (5x64), 320..331: p123 (3x4)
    __shared__ float occ[8];
    __shared__ float red[36];
    __shared__ float kdq_s[8];
    __shared__ float norm_s;
    __shared__ float kvred[256];

    const float PI_ = 3.14159265358979323846f;
    for (int t = 0; t < TT; ++t) {
        int row = t * BBATCH + b;
        const float* pr = proj + (size_t)row * NPROJ;
        __syncthreads();   // protect LDS overwrite vs previous iteration
        sp[tid] = pr[h*320 + tid];
        int t2 = tid + 256;
        if (t2 < 320) sp[t2] = pr[h*320 + t2];
        else if (t2 < 332) sp[t2] = pr[KQV + h*12 + (t2 - 320)];
        else if (t2 < 340) {
            int r = t2 - 332;
            occ[r] = cosf((tickb + (float)(t+1)) * (-PI_ + (float)r * (2.0f*PI_/7.0f)));
        }
        float mask = 1.0f - (float)term[row];
        __syncthreads();
        // per-e quantities
        float key = sp[d_e];
        float qry = sp[64 + d_e];
        float gam = sp[256 + d_e];
        float pp1 = sp[320 + p_e];
        float pp2 = sp[324 + p_e];
        float pp3 = sp[328 + p_e];
        float kexp = fmaxf(key, 0.f) * fmaxf(pp1, 0.f);
        float qexp = fmaxf(qry, 0.f) * fmaxf(pp2, 0.f);
        float gexp = sigmoidf_(gam) * sigmoidf_(pp3);
        float kg = kexp * gexp;
        float dg = (1.f - gexp) * mask;
        fs = dg * fs + kg;
        float sums[9];
        sums[8] = fs * qexp;
        #pragma unroll
        for (int r = 0; r < 8; ++r) {
            fk[r] = dg * fk[r] + kg * occ[r];
            sums[r] = fk[r] * qexp;
        }
        // 9 block reductions (wave shuffle + LDS combine)
        #pragma unroll
        for (int s2 = 0; s2 < 9; ++s2) {
            float v = sums[s2];
            #pragma unroll
            for (int off = 32; off; off >>= 1) v += __shfl_down(v, off);
            if ((tid & 63) == 0) red[s2*4 + (tid >> 6)] = v;
        }
        // final_values update (independent of kdq)
        float vv  = sp[128 + d0];
        float bet = sigmoidf_(sp[192 + d0]);
        float vg  = vv * bet;
        float db  = (1.f - bet) * mask;
        fv0 = db * fv0 + vg * occ[r0];
        fv1 = db * fv1 + vg * occ[r0 + 4];
        __syncthreads();
        if (tid < 9) {
            float v = red[tid*4] + red[tid*4+1] + red[tid*4+2] + red[tid*4+3];
            if (tid < 8) kdq_s[tid] = v;
            else         norm_s = v + 1e-6f;
        }
        __syncthreads();
        float kvc = fv0 * kdq_s[r0] + fv1 * kdq_s[r0 + 4];
        kvred[tid] = kvc;
        __syncthreads();
        if (tid < 64) {
            float kv = kvred[tid] + kvred[tid+64] + kvred[tid+128] + kvred[tid+192];
            attn[(size_t)row*512 + h*64 + tid] = kv / (16.f * norm_s);  // 2*R = 16
        }
    }
}

// ---------------- GRU elementwise phases ----------------------------------
// A1 = y@[w0;w1;w2]^T (M x 1536), Bx = x@[u0;u1]^T (M x 1024)
__global__ __launch_bounds__(256) void gru_rz_kernel(const float* __restrict__ A1,
    const float* __restrict__ Bx, const float* __restrict__ x,
    float* __restrict__ rx, float* __restrict__ z)
{
    size_t i = (size_t)blockIdx.x * 256 + threadIdx.x;
    size_t m = i >> 9;
    int c = (int)(i & 511);
    float rpre = A1[m*1536 + c]       + Bx[m*1024 + c];
    float zpre = A1[m*1536 + 512 + c] + Bx[m*1024 + 512 + c] - 2.0f;
    rx[i] = sigmoidf_(rpre) * x[i];
    z[i]  = sigmoidf_(zpre);
}

__global__ __launch_bounds__(256) void gru_final_kernel(const float* __restrict__ A1,
    const float* __restrict__ C2, const float* __restrict__ z,
    const float* __restrict__ x, float* __restrict__ out)
{
    size_t i = (size_t)blockIdx.x * 256 + threadIdx.x;
    size_t m = i >> 9;
    int c = (int)(i & 511);
    float hh = tanhf(A1[m*1536 + 1024 + c] + C2[i]);
    float zz = z[i];
    out[i] = (1.0f - zz) * x[i] + zz * hh;
}

// ---------------- launch --------------------------------------------------
extern "C" void kernel_launch(void* const* d_in, const int* in_sizes, int n_in,
                              void* d_out, int out_size, void* d_ws, size_t ws_size,
                              hipStream_t stream)
{
    const float* inputs = (const float*)d_in[0];
    const int*   term   = (const int*)  d_in[1];
    const float* tilde_k= (const float*)d_in[2];
    const float* tilde_v= (const float*)d_in[3];
    const float* s_prev = (const float*)d_in[4];
    const float* tick   = (const float*)d_in[5];
    const float* w_proj = (const float*)d_in[6];
    const float* b_proj = (const float*)d_in[7];
    const float* w_attn = (const float*)d_in[8];
    const float* b_attn = (const float*)d_in[9];
    const float* ln1_g  = (const float*)d_in[10];
    const float* ln1_b  = (const float*)d_in[11];
    const float* ln2_g  = (const float*)d_in[12];
    const float* ln2_b  = (const float*)d_in[13];
    const float* gru1_w = (const float*)d_in[14];
    const float* gru1_u = (const float*)d_in[15];
    const float* gru2_w = (const float*)d_in[16];
    const float* gru2_u = (const float*)d_in[17];
    const float* ffc_w1 = (const float*)d_in[18];
    const float* ffc_b1 = (const float*)d_in[19];
    const float* ffc_w2 = (const float*)d_in[20];
    const float* ffc_b2 = (const float*)d_in[21];
    float* out = (float*)d_out;
    float* ws  = (float*)d_ws;

    // workspace layout (floats). proj overlaid by A1/Bx/mid after scan consumes it.
    float* xn    = ws + 0;          // 4096*512
    float* attnb = ws + 2097152;    // 4096*512
    float* g1    = ws + 4194304;    // 4096*512
    float* y1    = ws + 6291456;    // 4096*512
    float* zb    = ws + 8388608;    // 4096*512
    float* rx    = ws + 10485760;   // 4096*512
    float* C2    = ws + 12582912;   // 4096*512
    float* ffin  = ws + 14680064;   // 4096*512
    float* ffout = ws + 16777216;   // 4096*512
    float* A1    = ws + 18874368;   // 4096*1536  (overlays proj)
    float* proj  = ws + 18874368;   // 4096*2656  (phase 1 only)
    float* Bx    = ws + 25165824;   // 4096*1024  (overlays proj)
    float* mid   = ws + 29360128;   // 4096*2048  (overlays proj tail)
    // total: 37,748,736 floats = 151 MB

    dim3 blk(256);
    const int grY = MM / 64;

    // 1. LN1 + projection
    ln_kernel<<<MM, blk, 0, stream>>>(inputs, ln1_g, ln1_b, xn);
    gemm_tn<<<dim3((NPROJ+63)/64, grY), blk, 0, stream>>>(xn, w_proj, b_proj, proj, MM, NPROJ, DM, 0);

    // 2. fused scans + attention contraction
    scan_attn_kernel<<<BBATCH*HH, blk, 0, stream>>>(proj, term, tick, tilde_k, tilde_v, s_prev, attnb);

    // 3. attn out-proj (+relu folded: y1 = relu(attn@w_attn^T + b_attn))
    gemm_tn<<<dim3(8, grY), blk, 0, stream>>>(attnb, w_attn, b_attn, y1, MM, DM, DM, 1);

    // 4. GRU1: x = inputs, y = y1
    gemm_tn<<<dim3(24, grY), blk, 0, stream>>>(y1, gru1_w, nullptr, A1, MM, 3*DM, DM, 0);
    gemm_tn<<<dim3(16, grY), blk, 0, stream>>>(inputs, gru1_u, nullptr, Bx, MM, 2*DM, DM, 0);
    gru_rz_kernel<<<MM*DM/256, blk, 0, stream>>>(A1, Bx, inputs, rx, zb);
    gemm_tn<<<dim3(8, grY), blk, 0, stream>>>(rx, gru1_u + 2*DM*DM, nullptr, C2, MM, DM, DM, 0);
    gru_final_kernel<<<MM*DM/256, blk, 0, stream>>>(A1, C2, zb, inputs, g1);

    // 5. LN2 + FFC
    ln_kernel<<<MM, blk, 0, stream>>>(g1, ln2_g, ln2_b, ffin);
    gemm_tn<<<dim3(32, grY), blk, 0, stream>>>(ffin, ffc_w1, ffc_b1, mid, MM, 2048, DM, 1);
    gemm_tn<<<dim3(8, grY), blk, 0, stream>>>(mid, ffc_w2, ffc_b2, ffout, MM, DM, 2048, 1);

    // 6. GRU2: x = g1, y = ffout
    gemm_tn<<<dim3(24, grY), blk, 0, stream>>>(ffout, gru2_w, nullptr, A1, MM, 3*DM, DM, 0);
    gemm_tn<<<dim3(16, grY), blk, 0, stream>>>(g1, gru2_u, nullptr, Bx, MM, 2*DM, DM, 0);
    gru_rz_kernel<<<MM*DM/256, blk, 0, stream>>>(A1, Bx, g1, rx, zb);
    gemm_tn<<<dim3(8, grY), blk, 0, stream>>>(rx, gru2_u + 2*DM*DM, nullptr, C2, MM, DM, DM, 0);
    gru_final_kernel<<<MM*DM/256, blk, 0, stream>>>(A1, C2, zb, g1, out);
}

// Round 2
// 1294.941 us; speedup vs baseline: 1.1065x; 1.1065x over previous
//
#include <hip/hip_runtime.h>
#include <math.h>

#define DM   512
#define HH   8
#define HDD  64
#define ETA_ 4
#define RR   8
#define TT   128
#define BBATCH 32
#define MM   (TT*BBATCH)     // 4096 rows
#define NPROJ 2656
#define KQV  2560

__device__ __forceinline__ float sigmoidf_(float x) {
    return 1.0f / (1.0f + __expf(-x));
}

// ---------------- LayerNorm (one row of 512 per block, 256 threads) -------
__global__ __launch_bounds__(256) void ln_kernel(const float* __restrict__ x,
    const float* __restrict__ g, const float* __restrict__ b,
    float* __restrict__ out)
{
    int row = blockIdx.x;
    int tid = threadIdx.x;
    const float* xr = x + (size_t)row * DM;
    float2 v = ((const float2*)xr)[tid];
    float s = v.x + v.y;
    #pragma unroll
    for (int off = 32; off; off >>= 1) s += __shfl_down(s, off);
    __shared__ float red[8];
    int wid = tid >> 6, lane = tid & 63;
    if (lane == 0) red[wid] = s;
    __syncthreads();
    if (tid == 0) red[0] = (red[0] + red[1] + red[2] + red[3]) * (1.0f / DM);
    __syncthreads();
    float mean = red[0];
    float dx = v.x - mean, dy = v.y - mean;
    float sq = dx*dx + dy*dy;
    #pragma unroll
    for (int off = 32; off; off >>= 1) sq += __shfl_down(sq, off);
    if (lane == 0) red[4 + wid] = sq;
    __syncthreads();
    if (tid == 0) red[1] = rsqrtf((red[4]+red[5]+red[6]+red[7]) * (1.0f/DM) + 1e-5f);
    __syncthreads();
    float rstd = red[1];
    float2 gg = ((const float2*)g)[tid];
    float2 bb = ((const float2*)b)[tid];
    float2 o;
    o.x = dx * rstd * gg.x + bb.x;
    o.y = dy * rstd * gg.y + bb.y;
    ((float2*)(out + (size_t)row * DM))[tid] = o;
}

// ---------------- f32 tiled GEMM: C[M,N] = act(A[M,K] @ W[N,K]^T + bias) --
#define BM 64
#define BN 64
#define BK 16

__global__ __launch_bounds__(256) void gemm_tn(const float* __restrict__ A,
    const float* __restrict__ W, const float* __restrict__ bias,
    float* __restrict__ C, int M, int N, int K, int act)
{
    __shared__ float As[BK][BM + 4];
    __shared__ float Ws[BK][BN + 4];
    int tid = threadIdx.x;
    int m0 = blockIdx.y * BM, n0 = blockIdx.x * BN;
    int lr = tid >> 2;             // 0..63: tile row
    int lk = (tid & 3) << 2;       // 0,4,8,12: k offset (float4)
    int tx = tid & 15, ty = tid >> 4;
    float acc[4][4] = {};
    for (int k0 = 0; k0 < K; k0 += BK) {
        float4 a4 = *(const float4*)(A + (size_t)(m0 + lr) * K + k0 + lk);
        float4 w4 = make_float4(0.f, 0.f, 0.f, 0.f);
        int wr = n0 + lr;
        if (wr < N) w4 = *(const float4*)(W + (size_t)wr * K + k0 + lk);
        __syncthreads();
        As[lk+0][lr] = a4.x; As[lk+1][lr] = a4.y; As[lk+2][lr] = a4.z; As[lk+3][lr] = a4.w;
        Ws[lk+0][lr] = w4.x; Ws[lk+1][lr] = w4.y; Ws[lk+2][lr] = w4.z; Ws[lk+3][lr] = w4.w;
        __syncthreads();
        #pragma unroll
        for (int k = 0; k < BK; ++k) {
            float a0 = As[k][ty*4+0], a1 = As[k][ty*4+1];
            float a2 = As[k][ty*4+2], a3 = As[k][ty*4+3];
            float b0 = Ws[k][tx*4+0], b1 = Ws[k][tx*4+1];
            float b2 = Ws[k][tx*4+2], b3 = Ws[k][tx*4+3];
            acc[0][0] += a0*b0; acc[0][1] += a0*b1; acc[0][2] += a0*b2; acc[0][3] += a0*b3;
            acc[1][0] += a1*b0; acc[1][1] += a1*b1; acc[1][2] += a1*b2; acc[1][3] += a1*b3;
            acc[2][0] += a2*b0; acc[2][1] += a2*b1; acc[2][2] += a2*b2; acc[2][3] += a2*b3;
            acc[3][0] += a3*b0; acc[3][1] += a3*b1; acc[3][2] += a3*b2; acc[3][3] += a3*b3;
        }
    }
    #pragma unroll
    for (int i = 0; i < 4; ++i) {
        int m = m0 + ty*4 + i;
        #pragma unroll
        for (int j = 0; j < 4; ++j) {
            int n = n0 + tx*4 + j;
            if (n < N) {
                float v = acc[i][j];
                if (bias) v += bias[n];
                if (act) v = fmaxf(v, 0.f);
                C[(size_t)m * N + n] = v;
            }
        }
    }
}

// ---------------- fused prepare + discounted scans + attention ------------
// ONE WAVE (64 lanes) per (b,h): 256 blocks x 64 threads. No LDS, no barriers.
// lane owns: d_e = lane (all 4 p_e), so per-lane state fs[4], fk[8][4];
// and d0 = lane for fv[8] (all r local) -> kv needs no reduction.
// kdq[8] + norm reduced via __shfl_xor butterflies (wave-local).
// proj/term loads for t+1 issued at top of iteration t (prefetch).
// Oscillator via rotation recurrence (2 FMA per r) instead of cosf.
__global__ __launch_bounds__(64) void scan_attn_wave(
    const float* __restrict__ proj, const int* __restrict__ term,
    const float* __restrict__ tick, const float* __restrict__ tilde_k,
    const float* __restrict__ tilde_v, const float* __restrict__ s_prev,
    float* __restrict__ attn)
{
    const int b = blockIdx.x >> 3;
    const int h = blockIdx.x & 7;
    const int lane = threadIdx.x;   // 0..63

    // ---- state in registers ----
    float4 fs = *(const float4*)(s_prev + ((size_t)(b*HH + h))*256 + lane*4);
    float4 fk[8];
    #pragma unroll
    for (int r = 0; r < 8; ++r)
        fk[r] = *(const float4*)(tilde_k + (((size_t)b*RR + r)*HH + h)*256 + lane*4);
    float fv[8];
    #pragma unroll
    for (int r = 0; r < 8; ++r)
        fv[r] = tilde_v[(((size_t)b*RR + r)*HH + h)*64 + lane];

    // ---- oscillator init: occ_r(t) = cos((tick + t + 1) * w_r) ----
    const float PI_ = 3.14159265358979323846f;
    float tk = tick[b];
    float cw[8], sw[8], oc[8], os[8];
    #pragma unroll
    for (int r = 0; r < 8; ++r) {
        float w = -PI_ + (float)r * (2.0f * PI_ / 7.0f);
        cw[r] = cosf(w); sw[r] = sinf(w);
        float a0 = (tk + 1.0f) * w;
        oc[r] = cosf(a0); os[r] = sinf(a0);
    }

    // ---- prefetch t = 0 ----
    const float* pr = proj + (size_t)(0*BBATCH + b) * NPROJ;
    float  pk  = pr[h*320 + lane];
    float  pq  = pr[h*320 + 64  + lane];
    float  pv  = pr[h*320 + 128 + lane];
    float  pbt = pr[h*320 + 192 + lane];
    float  pg  = pr[h*320 + 256 + lane];
    float4 pp1 = *(const float4*)(pr + KQV + h*12 + 0);
    float4 pp2 = *(const float4*)(pr + KQV + h*12 + 4);
    float4 pp3 = *(const float4*)(pr + KQV + h*12 + 8);
    int    ptm = term[0*BBATCH + b];

    for (int t = 0; t < TT; ++t) {
        // consume prefetched values
        float  key = pk,  qry = pq,  vv = pv,  bet = pbt, gam = pg;
        float4 q1 = pp1, q2 = pp2, q3 = pp3;
        int    tm = ptm;

        // issue t+1 loads (latency hidden behind this iteration's compute)
        if (t + 1 < TT) {
            const float* pn = proj + (size_t)((t+1)*BBATCH + b) * NPROJ;
            pk  = pn[h*320 + lane];
            pq  = pn[h*320 + 64  + lane];
            pv  = pn[h*320 + 128 + lane];
            pbt = pn[h*320 + 192 + lane];
            pg  = pn[h*320 + 256 + lane];
            pp1 = *(const float4*)(pn + KQV + h*12 + 0);
            pp2 = *(const float4*)(pn + KQV + h*12 + 4);
            pp3 = *(const float4*)(pn + KQV + h*12 + 8);
            ptm = term[(t+1)*BBATCH + b];
        }

        float mask = 1.0f - (float)tm;
        float kr = fmaxf(key, 0.f);
        float qr = fmaxf(qry, 0.f);
        float sg = sigmoidf_(gam);

        float p1a[4] = {q1.x, q1.y, q1.z, q1.w};
        float p2a[4] = {q2.x, q2.y, q2.z, q2.w};
        float p3a[4] = {q3.x, q3.y, q3.z, q3.w};
        float qexp[4], kg[4], dg[4];
        #pragma unroll
        for (int j = 0; j < 4; ++j) {
            float kexp = kr * fmaxf(p1a[j], 0.f);
            qexp[j]    = qr * fmaxf(p2a[j], 0.f);
            float gexp = sg * sigmoidf_(p3a[j]);
            kg[j] = kexp * gexp;
            dg[j] = (1.f - gexp) * mask;
        }

        // fs scan + norm partial
        float snorm;
        {
            fs.x = dg[0]*fs.x + kg[0];
            fs.y = dg[1]*fs.y + kg[1];
            fs.z = dg[2]*fs.z + kg[2];
            fs.w = dg[3]*fs.w + kg[3];
            snorm = fs.x*qexp[0] + fs.y*qexp[1] + fs.z*qexp[2] + fs.w*qexp[3];
        }

        // fk scans + kdq partials
        float kdq[8];
        #pragma unroll
        for (int r = 0; r < 8; ++r) {
            float4 f = fk[r];
            float o = oc[r];
            f.x = dg[0]*f.x + kg[0]*o;
            f.y = dg[1]*f.y + kg[1]*o;
            f.z = dg[2]*f.z + kg[2]*o;
            f.w = dg[3]*f.w + kg[3]*o;
            fk[r] = f;
            kdq[r] = f.x*qexp[0] + f.y*qexp[1] + f.z*qexp[2] + f.w*qexp[3];
        }

        // fv scan (lane owns d = lane, all r local)
        float sb = sigmoidf_(bet);
        float vg = vv * sb;
        float db = (1.f - sb) * mask;
        #pragma unroll
        for (int r = 0; r < 8; ++r)
            fv[r] = db * fv[r] + vg * oc[r];

        // rotate oscillator for next t
        #pragma unroll
        for (int r = 0; r < 8; ++r) {
            float c = oc[r], s = os[r];
            oc[r] = c*cw[r] - s*sw[r];
            os[r] = s*cw[r] + c*sw[r];
        }

        // wave-wide butterfly reductions: 8 kdq + snorm (all lanes get totals)
        #pragma unroll
        for (int m = 1; m < 64; m <<= 1) {
            snorm += __shfl_xor(snorm, m);
            #pragma unroll
            for (int r = 0; r < 8; ++r)
                kdq[r] += __shfl_xor(kdq[r], m);
        }

        // kv (lane-local over r) + store
        float kv = 0.f;
        #pragma unroll
        for (int r = 0; r < 8; ++r)
            kv += fv[r] * kdq[r];
        attn[(size_t)(t*BBATCH + b)*DM + h*64 + lane] = kv / (16.f * (snorm + 1e-6f));
    }
}

// ---------------- GRU elementwise phases ----------------------------------
__global__ __launch_bounds__(256) void gru_rz_kernel(const float* __restrict__ A1,
    const float* __restrict__ Bx, const float* __restrict__ x,
    float* __restrict__ rx, float* __restrict__ z)
{
    size_t i = (size_t)blockIdx.x * 256 + threadIdx.x;
    size_t m = i >> 9;
    int c = (int)(i & 511);
    float rpre = A1[m*1536 + c]       + Bx[m*1024 + c];
    float zpre = A1[m*1536 + 512 + c] + Bx[m*1024 + 512 + c] - 2.0f;
    rx[i] = sigmoidf_(rpre) * x[i];
    z[i]  = sigmoidf_(zpre);
}

__global__ __launch_bounds__(256) void gru_final_kernel(const float* __restrict__ A1,
    const float* __restrict__ C2, const float* __restrict__ z,
    const float* __restrict__ x, float* __restrict__ out)
{
    size_t i = (size_t)blockIdx.x * 256 + threadIdx.x;
    size_t m = i >> 9;
    int c = (int)(i & 511);
    float hh = tanhf(A1[m*1536 + 1024 + c] + C2[i]);
    float zz = z[i];
    out[i] = (1.0f - zz) * x[i] + zz * hh;
}

// ---------------- launch --------------------------------------------------
extern "C" void kernel_launch(void* const* d_in, const int* in_sizes, int n_in,
                              void* d_out, int out_size, void* d_ws, size_t ws_size,
                              hipStream_t stream)
{
    const float* inputs = (const float*)d_in[0];
    const int*   term   = (const int*)  d_in[1];
    const float* tilde_k= (const float*)d_in[2];
    const float* tilde_v= (const float*)d_in[3];
    const float* s_prev = (const float*)d_in[4];
    const float* tick   = (const float*)d_in[5];
    const float* w_proj = (const float*)d_in[6];
    const float* b_proj = (const float*)d_in[7];
    const float* w_attn = (const float*)d_in[8];
    const float* b_attn = (const float*)d_in[9];
    const float* ln1_g  = (const float*)d_in[10];
    const float* ln1_b  = (const float*)d_in[11];
    const float* ln2_g  = (const float*)d_in[12];
    const float* ln2_b  = (const float*)d_in[13];
    const float* gru1_w = (const float*)d_in[14];
    const float* gru1_u = (const float*)d_in[15];
    const float* gru2_w = (const float*)d_in[16];
    const float* gru2_u = (const float*)d_in[17];
    const float* ffc_w1 = (const float*)d_in[18];
    const float* ffc_b1 = (const float*)d_in[19];
    const float* ffc_w2 = (const float*)d_in[20];
    const float* ffc_b2 = (const float*)d_in[21];
    float* out = (float*)d_out;
    float* ws  = (float*)d_ws;

    // workspace layout (floats). proj overlaid by A1/Bx/mid after scan consumes it.
    float* xn    = ws + 0;          // 4096*512
    float* attnb = ws + 2097152;    // 4096*512
    float* g1    = ws + 4194304;    // 4096*512
    float* y1    = ws + 6291456;    // 4096*512
    float* zb    = ws + 8388608;    // 4096*512
    float* rx    = ws + 10485760;   // 4096*512
    float* C2    = ws + 12582912;   // 4096*512
    float* ffin  = ws + 14680064;   // 4096*512
    float* ffout = ws + 16777216;   // 4096*512
    float* A1    = ws + 18874368;   // 4096*1536  (overlays proj)
    float* proj  = ws + 18874368;   // 4096*2656  (phase 1 only)
    float* Bx    = ws + 25165824;   // 4096*1024  (overlays proj)
    float* mid   = ws + 29360128;   // 4096*2048  (overlays proj tail)

    dim3 blk(256);
    const int grY = MM / 64;

    // 1. LN1 + projection
    ln_kernel<<<MM, blk, 0, stream>>>(inputs, ln1_g, ln1_b, xn);
    gemm_tn<<<dim3((NPROJ+63)/64, grY), blk, 0, stream>>>(xn, w_proj, b_proj, proj, MM, NPROJ, DM, 0);

    // 2. fused scans + attention contraction (one wave per (b,h))
    scan_attn_wave<<<BBATCH*HH, dim3(64), 0, stream>>>(proj, term, tick, tilde_k, tilde_v, s_prev, attnb);

    // 3. attn out-proj (+relu folded)
    gemm_tn<<<dim3(8, grY), blk, 0, stream>>>(attnb, w_attn, b_attn, y1, MM, DM, DM, 1);

    // 4. GRU1: x = inputs, y = y1
    gemm_tn<<<dim3(24, grY), blk, 0, stream>>>(y1, gru1_w, nullptr, A1, MM, 3*DM, DM, 0);
    gemm_tn<<<dim3(16, grY), blk, 0, stream>>>(inputs, gru1_u, nullptr, Bx, MM, 2*DM, DM, 0);
    gru_rz_kernel<<<MM*DM/256, blk, 0, stream>>>(A1, Bx, inputs, rx, zb);
    gemm_tn<<<dim3(8, grY), blk, 0, stream>>>(rx, gru1_u + 2*DM*DM, nullptr, C2, MM, DM, DM, 0);
    gru_final_kernel<<<MM*DM/256, blk, 0, stream>>>(A1, C2, zb, inputs, g1);

    // 5. LN2 + FFC
    ln_kernel<<<MM, blk, 0, stream>>>(g1, ln2_g, ln2_b, ffin);
    gemm_tn<<<dim3(32, grY), blk, 0, stream>>>(ffin, ffc_w1, ffc_b1, mid, MM, 2048, DM, 1);
    gemm_tn<<<dim3(8, grY), blk, 0, stream>>>(mid, ffc_w2, ffc_b2, ffout, MM, DM, 2048, 1);

    // 6. GRU2: x = g1, y = ffout
    gemm_tn<<<dim3(24, grY), blk, 0, stream>>>(ffout, gru2_w, nullptr, A1, MM, 3*DM, DM, 0);
    gemm_tn<<<dim3(16, grY), blk, 0, stream>>>(g1, gru2_u, nullptr, Bx, MM, 2*DM, DM, 0);
    gru_rz_kernel<<<MM*DM/256, blk, 0, stream>>>(A1, Bx, g1, rx, zb);
    gemm_tn<<<dim3(8, grY), blk, 0, stream>>>(rx, gru2_u + 2*DM*DM, nullptr, C2, MM, DM, DM, 0);
    gru_final_kernel<<<MM*DM/256, blk, 0, stream>>>(A1, C2, zb, g1, out);
}

// Round 3
// 609.125 us; speedup vs baseline: 2.3523x; 2.1259x over previous
//
#include <hip/hip_runtime.h>
#include <hip/hip_bf16.h>
#include <math.h>

#define DM   512
#define HH   8
#define RR   8
#define TT   128
#define BBATCH 32
#define MM   (TT*BBATCH)     // 4096 rows
#define NPROJ 2656
#define KQV  2560

typedef __attribute__((ext_vector_type(8))) short bf16x8;
typedef __attribute__((ext_vector_type(4))) float f32x4;

__device__ __forceinline__ float sigmoidf_(float x) {
    return 1.0f / (1.0f + __expf(-x));
}

__device__ __forceinline__ void gload_lds16(const void* g, void* l) {
    __builtin_amdgcn_global_load_lds(
        (const __attribute__((address_space(1))) unsigned int*)g,
        (__attribute__((address_space(3))) unsigned int*)l, 16, 0, 0);
}

// ---------------- f32 -> bf16 conversion (grid-stride over /4) ------------
__global__ __launch_bounds__(256) void f2b_kernel(const float* __restrict__ in,
    __hip_bfloat16* __restrict__ out, int n)
{
    int i = (blockIdx.x * 256 + threadIdx.x) * 4;
    if (i < n) {
        float4 v = *(const float4*)(in + i);
        out[i+0] = __float2bfloat16(v.x);
        out[i+1] = __float2bfloat16(v.y);
        out[i+2] = __float2bfloat16(v.z);
        out[i+3] = __float2bfloat16(v.w);
    }
}

// ---------------- LayerNorm -> bf16 out -----------------------------------
__global__ __launch_bounds__(256) void ln_kernel(const float* __restrict__ x,
    const float* __restrict__ g, const float* __restrict__ b,
    __hip_bfloat16* __restrict__ out)
{
    int row = blockIdx.x;
    int tid = threadIdx.x;
    const float* xr = x + (size_t)row * DM;
    float2 v = ((const float2*)xr)[tid];
    float s = v.x + v.y;
    #pragma unroll
    for (int off = 32; off; off >>= 1) s += __shfl_down(s, off);
    __shared__ float red[8];
    int wid = tid >> 6, lane = tid & 63;
    if (lane == 0) red[wid] = s;
    __syncthreads();
    if (tid == 0) red[0] = (red[0] + red[1] + red[2] + red[3]) * (1.0f / DM);
    __syncthreads();
    float mean = red[0];
    float dx = v.x - mean, dy = v.y - mean;
    float sq = dx*dx + dy*dy;
    #pragma unroll
    for (int off = 32; off; off >>= 1) sq += __shfl_down(sq, off);
    if (lane == 0) red[4 + wid] = sq;
    __syncthreads();
    if (tid == 0) red[1] = rsqrtf((red[4]+red[5]+red[6]+red[7]) * (1.0f/DM) + 1e-5f);
    __syncthreads();
    float rstd = red[1];
    float2 gg = ((const float2*)g)[tid];
    float2 bb = ((const float2*)b)[tid];
    __hip_bfloat16* orow = out + (size_t)row * DM;
    orow[2*tid+0] = __float2bfloat16(dx * rstd * gg.x + bb.x);
    orow[2*tid+1] = __float2bfloat16(dy * rstd * gg.y + bb.y);
}

// ---------------- bf16 MFMA GEMM: C = act(A[MxK] @ W[NxK]^T + bias) -------
// 128x128 tile, BK=32, 256 threads = 4 waves (2x2 of 64x64).
// LDS layout = fragment order: slot(chunk, lane) holds
//   X[tile_row = chunk*16 + (lane&15)][k = (lane>>4)*8 .. +7]
// -> ds_read_b128 at base+lane*16 (conflict-free), and global_load_lds's
//    wave-uniform-base + lane*16 dest constraint is satisfied.
__global__ __launch_bounds__(256) void gemm_bf16(
    const __hip_bfloat16* __restrict__ A,   // M x K
    const __hip_bfloat16* __restrict__ W,   // N x K
    const float* __restrict__ bias,
    float* __restrict__ Cf, __hip_bfloat16* __restrict__ Cb,
    int M, int N, int K, int act)
{
    __shared__ __attribute__((aligned(16))) __hip_bfloat16 As[8*512];  // 8 KB
    __shared__ __attribute__((aligned(16))) __hip_bfloat16 Bs[8*512];  // 8 KB
    int tid = threadIdx.x;
    int wave = tid >> 6, lane = tid & 63;
    int m0 = blockIdx.y * 128, n0 = blockIdx.x * 128;
    int wm = (wave >> 1) * 64, wn = (wave & 1) * 64;
    int fr = lane & 15;       // row within 16-tile
    int fq = lane >> 4;       // k-quad (8 elems each)

    f32x4 acc[4][4];
    #pragma unroll
    for (int i = 0; i < 4; ++i)
        #pragma unroll
        for (int j = 0; j < 4; ++j)
            acc[i][j] = (f32x4){0.f, 0.f, 0.f, 0.f};

    // staging source rows for this thread (chunks wave and wave+4)
    int sm0 = wave*16 + fr;
    int sm1 = sm0 + 64;
    int wr0 = n0 + sm0; if (wr0 >= N) wr0 = N - 1;
    int wr1 = n0 + sm1; if (wr1 >= N) wr1 = N - 1;
    const __hip_bfloat16* Ag0 = A + (size_t)(m0 + sm0) * K + fq*8;
    const __hip_bfloat16* Ag1 = A + (size_t)(m0 + sm1) * K + fq*8;
    const __hip_bfloat16* Wg0 = W + (size_t)wr0 * K + fq*8;
    const __hip_bfloat16* Wg1 = W + (size_t)wr1 * K + fq*8;

    for (int k0 = 0; k0 < K; k0 += 32) {
        gload_lds16(Ag0 + k0, As + (size_t)wave*512);
        gload_lds16(Ag1 + k0, As + (size_t)(wave+4)*512);
        gload_lds16(Wg0 + k0, Bs + (size_t)wave*512);
        gload_lds16(Wg1 + k0, Bs + (size_t)(wave+4)*512);
        __syncthreads();   // drains global_load_lds (vmcnt) + barrier
        bf16x8 af[4], bfr[4];
        #pragma unroll
        for (int i = 0; i < 4; ++i) {
            af[i]  = *(const bf16x8*)(As + (size_t)(wm/16 + i)*512 + lane*8);
            bfr[i] = *(const bf16x8*)(Bs + (size_t)(wn/16 + i)*512 + lane*8);
        }
        #pragma unroll
        for (int mi = 0; mi < 4; ++mi)
            #pragma unroll
            for (int ni = 0; ni < 4; ++ni)
                acc[mi][ni] = __builtin_amdgcn_mfma_f32_16x16x32_bf16(
                    af[mi], bfr[ni], acc[mi][ni], 0, 0, 0);
        __syncthreads();   // all reads done before next overwrite
    }

    // epilogue: C/D layout col = lane&15, row = (lane>>4)*4 + reg
    #pragma unroll
    for (int ni = 0; ni < 4; ++ni) {
        int n = n0 + wn + ni*16 + fr;
        bool nok = n < N;
        float bv = (bias && nok) ? bias[n] : 0.f;
        #pragma unroll
        for (int mi = 0; mi < 4; ++mi) {
            #pragma unroll
            for (int r = 0; r < 4; ++r) {
                int m = m0 + wm + mi*16 + fq*4 + r;
                float v = acc[mi][ni][r] + bv;
                if (act) v = fmaxf(v, 0.f);
                if (nok) {
                    size_t idx = (size_t)m * N + n;
                    if (Cf) Cf[idx] = v;
                    if (Cb) Cb[idx] = __float2bfloat16(v);
                }
            }
        }
    }
}

// ---------------- fused scans + attention, one wave per (b,h) -------------
// Depth-2 software prefetch: loads for t+2 issued while computing t.
__global__ __launch_bounds__(64) void scan_attn_wave(
    const float* __restrict__ proj, const int* __restrict__ term,
    const float* __restrict__ tick, const float* __restrict__ tilde_k,
    const float* __restrict__ tilde_v, const float* __restrict__ s_prev,
    __hip_bfloat16* __restrict__ attn)
{
    const int b = blockIdx.x >> 3;
    const int h = blockIdx.x & 7;
    const int lane = threadIdx.x;

    float4 fs = *(const float4*)(s_prev + ((size_t)(b*HH + h))*256 + lane*4);
    float4 fk[8];
    #pragma unroll
    for (int r = 0; r < 8; ++r)
        fk[r] = *(const float4*)(tilde_k + (((size_t)b*RR + r)*HH + h)*256 + lane*4);
    float fv[8];
    #pragma unroll
    for (int r = 0; r < 8; ++r)
        fv[r] = tilde_v[(((size_t)b*RR + r)*HH + h)*64 + lane];

    const float PI_ = 3.14159265358979323846f;
    float tk = tick[b];
    float cw[8], sw[8], oc[8], os[8];
    #pragma unroll
    for (int r = 0; r < 8; ++r) {
        float w = -PI_ + (float)r * (2.0f * PI_ / 7.0f);
        cw[r] = cosf(w); sw[r] = sinf(w);
        float a0 = (tk + 1.0f) * w;
        oc[r] = cosf(a0); os[r] = sinf(a0);
    }

    struct PF { float k, q, v, bt, g; float4 p1, p2, p3; int tm; };
    auto loadPF = [&](int t, PF& p) {
        if (t < TT) {
            const float* pn = proj + (size_t)(t*BBATCH + b) * NPROJ + h*320;
            p.k  = pn[lane];
            p.q  = pn[64  + lane];
            p.v  = pn[128 + lane];
            p.bt = pn[192 + lane];
            p.g  = pn[256 + lane];
            const float* pe = proj + (size_t)(t*BBATCH + b) * NPROJ + KQV + h*12;
            p.p1 = *(const float4*)(pe);
            p.p2 = *(const float4*)(pe + 4);
            p.p3 = *(const float4*)(pe + 8);
            p.tm = term[t*BBATCH + b];
        }
    };

    auto step = [&](int t, PF c) {
        float mask = 1.0f - (float)c.tm;
        float kr = fmaxf(c.k, 0.f);
        float qr = fmaxf(c.q, 0.f);
        float sg = sigmoidf_(c.g);
        float p1a[4] = {c.p1.x, c.p1.y, c.p1.z, c.p1.w};
        float p2a[4] = {c.p2.x, c.p2.y, c.p2.z, c.p2.w};
        float p3a[4] = {c.p3.x, c.p3.y, c.p3.z, c.p3.w};
        float qexp[4], kg[4], dg[4];
        #pragma unroll
        for (int j = 0; j < 4; ++j) {
            float kexp = kr * fmaxf(p1a[j], 0.f);
            qexp[j]    = qr * fmaxf(p2a[j], 0.f);
            float gexp = sg * sigmoidf_(p3a[j]);
            kg[j] = kexp * gexp;
            dg[j] = (1.f - gexp) * mask;
        }
        fs.x = dg[0]*fs.x + kg[0];
        fs.y = dg[1]*fs.y + kg[1];
        fs.z = dg[2]*fs.z + kg[2];
        fs.w = dg[3]*fs.w + kg[3];
        float snorm = fs.x*qexp[0] + fs.y*qexp[1] + fs.z*qexp[2] + fs.w*qexp[3];
        float kdq[8];
        #pragma unroll
        for (int r = 0; r < 8; ++r) {
            float4 f = fk[r];
            float o = oc[r];
            f.x = dg[0]*f.x + kg[0]*o;
            f.y = dg[1]*f.y + kg[1]*o;
            f.z = dg[2]*f.z + kg[2]*o;
            f.w = dg[3]*f.w + kg[3]*o;
            fk[r] = f;
            kdq[r] = f.x*qexp[0] + f.y*qexp[1] + f.z*qexp[2] + f.w*qexp[3];
        }
        float sb = sigmoidf_(c.bt);
        float vg = c.v * sb;
        float db = (1.f - sb) * mask;
        #pragma unroll
        for (int r = 0; r < 8; ++r)
            fv[r] = db * fv[r] + vg * oc[r];
        #pragma unroll
        for (int r = 0; r < 8; ++r) {
            float cc = oc[r], ss = os[r];
            oc[r] = cc*cw[r] - ss*sw[r];
            os[r] = ss*cw[r] + cc*sw[r];
        }
        #pragma unroll
        for (int m = 1; m < 64; m <<= 1) {
            snorm += __shfl_xor(snorm, m);
            #pragma unroll
            for (int r = 0; r < 8; ++r)
                kdq[r] += __shfl_xor(kdq[r], m);
        }
        float kv = 0.f;
        #pragma unroll
        for (int r = 0; r < 8; ++r)
            kv += fv[r] * kdq[r];
        attn[(size_t)(t*BBATCH + b)*DM + h*64 + lane] =
            __float2bfloat16(kv / (16.f * (snorm + 1e-6f)));
    };

    PF pf0, pf1;
    loadPF(0, pf0);
    loadPF(1, pf1);
    for (int t = 0; t < TT; t += 2) {
        PF c0 = pf0; loadPF(t + 2, pf0);
        step(t, c0);
        PF c1 = pf1; loadPF(t + 3, pf1);
        step(t + 1, c1);
    }
}

// ---------------- GRU elementwise phases ----------------------------------
__global__ __launch_bounds__(256) void gru_rz_kernel(const float* __restrict__ A1,
    const float* __restrict__ Bx, const float* __restrict__ x,
    __hip_bfloat16* __restrict__ rx, float* __restrict__ z)
{
    size_t i = (size_t)blockIdx.x * 256 + threadIdx.x;
    size_t m = i >> 9;
    int c = (int)(i & 511);
    float rpre = A1[m*1536 + c]       + Bx[m*1024 + c];
    float zpre = A1[m*1536 + 512 + c] + Bx[m*1024 + 512 + c] - 2.0f;
    rx[i] = __float2bfloat16(sigmoidf_(rpre) * x[i]);
    z[i]  = sigmoidf_(zpre);
}

__global__ __launch_bounds__(256) void gru_final_kernel(const float* __restrict__ A1,
    const float* __restrict__ C2, const float* __restrict__ z,
    const float* __restrict__ x, float* __restrict__ out,
    __hip_bfloat16* __restrict__ outb)
{
    size_t i = (size_t)blockIdx.x * 256 + threadIdx.x;
    size_t m = i >> 9;
    int c = (int)(i & 511);
    float hh = tanhf(A1[m*1536 + 1024 + c] + C2[i]);
    float zz = z[i];
    float v = (1.0f - zz) * x[i] + zz * hh;
    out[i] = v;
    if (outb) outb[i] = __float2bfloat16(v);
}

// ---------------- launch --------------------------------------------------
extern "C" void kernel_launch(void* const* d_in, const int* in_sizes, int n_in,
                              void* d_out, int out_size, void* d_ws, size_t ws_size,
                              hipStream_t stream)
{
    const float* inputs = (const float*)d_in[0];
    const int*   term   = (const int*)  d_in[1];
    const float* tilde_k= (const float*)d_in[2];
    const float* tilde_v= (const float*)d_in[3];
    const float* s_prev = (const float*)d_in[4];
    const float* tick   = (const float*)d_in[5];
    const float* w_proj = (const float*)d_in[6];
    const float* b_proj = (const float*)d_in[7];
    const float* w_attn = (const float*)d_in[8];
    const float* b_attn = (const float*)d_in[9];
    const float* ln1_g  = (const float*)d_in[10];
    const float* ln1_b  = (const float*)d_in[11];
    const float* ln2_g  = (const float*)d_in[12];
    const float* ln2_b  = (const float*)d_in[13];
    const float* gru1_w = (const float*)d_in[14];
    const float* gru1_u = (const float*)d_in[15];
    const float* gru2_w = (const float*)d_in[16];
    const float* gru2_u = (const float*)d_in[17];
    const float* ffc_w1 = (const float*)d_in[18];
    const float* ffc_b1 = (const float*)d_in[19];
    const float* ffc_w2 = (const float*)d_in[20];
    const float* ffc_b2 = (const float*)d_in[21];
    float* out = (float*)d_out;
    float* ws  = (float*)d_ws;

    // ---- f32 region (floats) ----
    float* proj = ws;                       // 10,878,976 (4096x2656)
    float* A1   = ws;                       // 4096x1536 (overlays proj after scan)
    float* Bx   = ws + 6291456;             // 4096x1024 (overlays proj tail)
    float* C2   = ws + 10878976;            // 4096x512
    float* zb   = ws + 12976128;            // 4096x512
    float* g1   = ws + 15073280;            // 4096x512
    // ---- bf16 region (halves), base at float offset 17,170,432 ----
    __hip_bfloat16* bb = (__hip_bfloat16*)(ws + 17170432);
    __hip_bfloat16* wp_bf  = bb + 0;          // 2656x512
    __hip_bfloat16* wat_bf = bb + 1359872;    // 512x512
    __hip_bfloat16* g1w_bf = bb + 1622016;    // 3x512x512
    __hip_bfloat16* g1u_bf = bb + 2408448;    // 3x512x512
    __hip_bfloat16* g2w_bf = bb + 3194880;
    __hip_bfloat16* g2u_bf = bb + 3981312;
    __hip_bfloat16* fw1_bf = bb + 4767744;    // 2048x512
    __hip_bfloat16* fw2_bf = bb + 5816320;    // 512x2048
    __hip_bfloat16* in_bf  = bb + 6864896;    // 4096x512
    __hip_bfloat16* xn_bf  = bb + 8962048;
    __hip_bfloat16* at_bf  = bb + 11059200;
    __hip_bfloat16* y1_bf  = bb + 13156352;
    __hip_bfloat16* rx_bf  = bb + 15253504;
    __hip_bfloat16* fi_bf  = bb + 17350656;
    __hip_bfloat16* mid_bf = bb + 19447808;   // 4096x2048
    __hip_bfloat16* fo_bf  = bb + 27836416;
    __hip_bfloat16* g1_bf  = bb + 29933568;
    // total ws use: 132.7 MB

    dim3 blk(256);
    #define F2B(src, dst, n) f2b_kernel<<<((n)/4 + 255)/256, blk, 0, stream>>>(src, dst, n)
    F2B(w_proj, wp_bf, 1359872);
    F2B(w_attn, wat_bf, 262144);
    F2B(gru1_w, g1w_bf, 786432);
    F2B(gru1_u, g1u_bf, 786432);
    F2B(gru2_w, g2w_bf, 786432);
    F2B(gru2_u, g2u_bf, 786432);
    F2B(ffc_w1, fw1_bf, 1048576);
    F2B(ffc_w2, fw2_bf, 1048576);
    F2B(inputs, in_bf, 2097152);

    // 1. LN1 + projection
    ln_kernel<<<MM, blk, 0, stream>>>(inputs, ln1_g, ln1_b, xn_bf);
    gemm_bf16<<<dim3(21, 32), blk, 0, stream>>>(xn_bf, wp_bf, b_proj, proj, nullptr, MM, NPROJ, DM, 0);

    // 2. fused scans + attention (one wave per (b,h), depth-2 prefetch)
    scan_attn_wave<<<BBATCH*HH, dim3(64), 0, stream>>>(proj, term, tick, tilde_k, tilde_v, s_prev, at_bf);

    // 3. attn out-proj (+relu)
    gemm_bf16<<<dim3(4, 32), blk, 0, stream>>>(at_bf, wat_bf, b_attn, nullptr, y1_bf, MM, DM, DM, 1);

    // 4. GRU1: x = inputs, y = y1
    gemm_bf16<<<dim3(12, 32), blk, 0, stream>>>(y1_bf, g1w_bf, nullptr, A1, nullptr, MM, 3*DM, DM, 0);
    gemm_bf16<<<dim3(8, 32),  blk, 0, stream>>>(in_bf, g1u_bf, nullptr, Bx, nullptr, MM, 2*DM, DM, 0);
    gru_rz_kernel<<<MM*DM/256, blk, 0, stream>>>(A1, Bx, inputs, rx_bf, zb);
    gemm_bf16<<<dim3(4, 32),  blk, 0, stream>>>(rx_bf, g1u_bf + 2*DM*DM, nullptr, C2, nullptr, MM, DM, DM, 0);
    gru_final_kernel<<<MM*DM/256, blk, 0, stream>>>(A1, C2, zb, inputs, g1, g1_bf);

    // 5. LN2 + FFC
    ln_kernel<<<MM, blk, 0, stream>>>(g1, ln2_g, ln2_b, fi_bf);
    gemm_bf16<<<dim3(16, 32), blk, 0, stream>>>(fi_bf, fw1_bf, ffc_b1, nullptr, mid_bf, MM, 2048, DM, 1);
    gemm_bf16<<<dim3(4, 32),  blk, 0, stream>>>(mid_bf, fw2_bf, ffc_b2, nullptr, fo_bf, MM, DM, 2048, 1);

    // 6. GRU2: x = g1, y = ffout
    gemm_bf16<<<dim3(12, 32), blk, 0, stream>>>(fo_bf, g2w_bf, nullptr, A1, nullptr, MM, 3*DM, DM, 0);
    gemm_bf16<<<dim3(8, 32),  blk, 0, stream>>>(g1_bf, g2u_bf, nullptr, Bx, nullptr, MM, 2*DM, DM, 0);
    gru_rz_kernel<<<MM*DM/256, blk, 0, stream>>>(A1, Bx, g1, rx_bf, zb);
    gemm_bf16<<<dim3(4, 32),  blk, 0, stream>>>(rx_bf, g2u_bf + 2*DM*DM, nullptr, C2, nullptr, MM, DM, DM, 0);
    gru_final_kernel<<<MM*DM/256, blk, 0, stream>>>(A1, C2, zb, g1, out, nullptr);
}

// Round 4
// 546.543 us; speedup vs baseline: 2.6216x; 1.1145x over previous
//
#include <hip/hip_runtime.h>
#include <hip/hip_bf16.h>
#include <math.h>

#define DM   512
#define HH   8
#define RR   8
#define TT   128
#define BBATCH 32
#define MM   (TT*BBATCH)     // 4096 rows
#define NPROJ 2656
#define KQV  2560

typedef __attribute__((ext_vector_type(8))) short bf16x8;
typedef __attribute__((ext_vector_type(4))) float f32x4;

__device__ __forceinline__ float sigmoidf_(float x) {
    return 1.0f / (1.0f + __expf(-x));
}

__device__ __forceinline__ void gload_lds16(const void* g, void* l) {
    __builtin_amdgcn_global_load_lds(
        (const __attribute__((address_space(1))) unsigned int*)g,
        (__attribute__((address_space(3))) unsigned int*)l, 16, 0, 0);
}

// ---------------- merged f32 -> bf16 conversions (9 segments, 1 launch) ---
struct F2B9 {
    const float* s[9];
    __hip_bfloat16* d[9];
    int cum[10];   // cumulative quad (float4) counts
};

__global__ __launch_bounds__(256) void f2b_all(F2B9 a)
{
    int q = blockIdx.x * 256 + threadIdx.x;
    if (q >= a.cum[9]) return;
    int s = 0;
    #pragma unroll
    for (int i = 1; i < 9; ++i) s += (q >= a.cum[i]);
    int i4 = (q - a.cum[s]) * 4;
    float4 v = *(const float4*)(a.s[s] + i4);
    __hip_bfloat16* dst = a.d[s] + i4;
    dst[0] = __float2bfloat16(v.x);
    dst[1] = __float2bfloat16(v.y);
    dst[2] = __float2bfloat16(v.z);
    dst[3] = __float2bfloat16(v.w);
}

// ---------------- LayerNorm -> bf16 out -----------------------------------
__global__ __launch_bounds__(256) void ln_kernel(const float* __restrict__ x,
    const float* __restrict__ g, const float* __restrict__ b,
    __hip_bfloat16* __restrict__ out)
{
    int row = blockIdx.x;
    int tid = threadIdx.x;
    const float* xr = x + (size_t)row * DM;
    float2 v = ((const float2*)xr)[tid];
    float s = v.x + v.y;
    #pragma unroll
    for (int off = 32; off; off >>= 1) s += __shfl_down(s, off);
    __shared__ float red[8];
    int wid = tid >> 6, lane = tid & 63;
    if (lane == 0) red[wid] = s;
    __syncthreads();
    if (tid == 0) red[0] = (red[0] + red[1] + red[2] + red[3]) * (1.0f / DM);
    __syncthreads();
    float mean = red[0];
    float dx = v.x - mean, dy = v.y - mean;
    float sq = dx*dx + dy*dy;
    #pragma unroll
    for (int off = 32; off; off >>= 1) sq += __shfl_down(sq, off);
    if (lane == 0) red[4 + wid] = sq;
    __syncthreads();
    if (tid == 0) red[1] = rsqrtf((red[4]+red[5]+red[6]+red[7]) * (1.0f/DM) + 1e-5f);
    __syncthreads();
    float rstd = red[1];
    float2 gg = ((const float2*)g)[tid];
    float2 bb = ((const float2*)b)[tid];
    __hip_bfloat16* orow = out + (size_t)row * DM;
    orow[2*tid+0] = __float2bfloat16(dx * rstd * gg.x + bb.x);
    orow[2*tid+1] = __float2bfloat16(dy * rstd * gg.y + bb.y);
}

// ---------------- bf16 MFMA GEMM core: 128x128 tile, BK=32 ----------------
// LDS fragment-order layout; per-element k-accumulation order is fixed
// (sequential 32-chunks, one MFMA chain) -> numerics independent of grid.
__device__ __forceinline__ void gemm_core128(
    const __hip_bfloat16* __restrict__ A, const __hip_bfloat16* __restrict__ W,
    const float* __restrict__ bias,
    float* __restrict__ Cf, __hip_bfloat16* __restrict__ Cb,
    int N, int K, int act, int m0, int n0)
{
    __shared__ __attribute__((aligned(16))) __hip_bfloat16 As[8*512];
    __shared__ __attribute__((aligned(16))) __hip_bfloat16 Bs[8*512];
    int tid = threadIdx.x;
    int wave = tid >> 6, lane = tid & 63;
    int wm = (wave >> 1) * 64, wn = (wave & 1) * 64;
    int fr = lane & 15, fq = lane >> 4;

    f32x4 acc[4][4];
    #pragma unroll
    for (int i = 0; i < 4; ++i)
        #pragma unroll
        for (int j = 0; j < 4; ++j)
            acc[i][j] = (f32x4){0.f, 0.f, 0.f, 0.f};

    int sm0 = wave*16 + fr;
    int sm1 = sm0 + 64;
    int wr0 = n0 + sm0; if (wr0 >= N) wr0 = N - 1;
    int wr1 = n0 + sm1; if (wr1 >= N) wr1 = N - 1;
    const __hip_bfloat16* Ag0 = A + (size_t)(m0 + sm0) * K + fq*8;
    const __hip_bfloat16* Ag1 = A + (size_t)(m0 + sm1) * K + fq*8;
    const __hip_bfloat16* Wg0 = W + (size_t)wr0 * K + fq*8;
    const __hip_bfloat16* Wg1 = W + (size_t)wr1 * K + fq*8;

    for (int k0 = 0; k0 < K; k0 += 32) {
        gload_lds16(Ag0 + k0, As + (size_t)wave*512);
        gload_lds16(Ag1 + k0, As + (size_t)(wave+4)*512);
        gload_lds16(Wg0 + k0, Bs + (size_t)wave*512);
        gload_lds16(Wg1 + k0, Bs + (size_t)(wave+4)*512);
        __syncthreads();
        bf16x8 af[4], bfr[4];
        #pragma unroll
        for (int i = 0; i < 4; ++i) {
            af[i]  = *(const bf16x8*)(As + (size_t)(wm/16 + i)*512 + lane*8);
            bfr[i] = *(const bf16x8*)(Bs + (size_t)(wn/16 + i)*512 + lane*8);
        }
        #pragma unroll
        for (int mi = 0; mi < 4; ++mi)
            #pragma unroll
            for (int ni = 0; ni < 4; ++ni)
                acc[mi][ni] = __builtin_amdgcn_mfma_f32_16x16x32_bf16(
                    af[mi], bfr[ni], acc[mi][ni], 0, 0, 0);
        __syncthreads();
    }

    #pragma unroll
    for (int ni = 0; ni < 4; ++ni) {
        int n = n0 + wn + ni*16 + fr;
        bool nok = n < N;
        float bv = (bias && nok) ? bias[n] : 0.f;
        #pragma unroll
        for (int mi = 0; mi < 4; ++mi) {
            #pragma unroll
            for (int r = 0; r < 4; ++r) {
                int m = m0 + wm + mi*16 + fq*4 + r;
                float v = acc[mi][ni][r] + bv;
                if (act) v = fmaxf(v, 0.f);
                if (nok) {
                    size_t idx = (size_t)m * N + n;
                    if (Cf) Cf[idx] = v;
                    if (Cb) Cb[idx] = __float2bfloat16(v);
                }
            }
        }
    }
}

__global__ __launch_bounds__(256) void gemm_bf16(
    const __hip_bfloat16* __restrict__ A, const __hip_bfloat16* __restrict__ W,
    const float* __restrict__ bias,
    float* __restrict__ Cf, __hip_bfloat16* __restrict__ Cb,
    int N, int K, int act)
{
    gemm_core128(A, W, bias, Cf, Cb, N, K, act, blockIdx.y * 128, blockIdx.x * 128);
}

// dual-source GEMM: blocks [0,splitX) compute Ca = Aa@Wa^T, rest Cb2 = Ab@Wb^T
__global__ __launch_bounds__(256) void gemm_bf16_dual(
    const __hip_bfloat16* __restrict__ Aa, const __hip_bfloat16* __restrict__ Wa,
    float* __restrict__ Ca, int Na, int splitX,
    const __hip_bfloat16* __restrict__ Ab, const __hip_bfloat16* __restrict__ Wb,
    float* __restrict__ Cb2, int Nb, int K)
{
    int bx = blockIdx.x;
    if (bx < splitX)
        gemm_core128(Aa, Wa, nullptr, Ca, nullptr, Na, K, 0, blockIdx.y*128, bx*128);
    else
        gemm_core128(Ab, Wb, nullptr, Cb2, nullptr, Nb, K, 0, blockIdx.y*128, (bx-splitX)*128);
}

// ---------------- 64x128-tile GEMM (for N=512 cases: 256 blocks) ----------
__global__ __launch_bounds__(256) void gemm_bf16_64(
    const __hip_bfloat16* __restrict__ A, const __hip_bfloat16* __restrict__ W,
    const float* __restrict__ bias,
    float* __restrict__ Cf, __hip_bfloat16* __restrict__ Cb,
    int N, int K, int act)
{
    __shared__ __attribute__((aligned(16))) __hip_bfloat16 As[4*512];
    __shared__ __attribute__((aligned(16))) __hip_bfloat16 Bs[8*512];
    int tid = threadIdx.x;
    int wave = tid >> 6, lane = tid & 63;
    int m0 = blockIdx.y * 64, n0 = blockIdx.x * 128;
    int wm = (wave >> 1) * 32, wn = (wave & 1) * 64;
    int fr = lane & 15, fq = lane >> 4;

    f32x4 acc[2][4];
    #pragma unroll
    for (int i = 0; i < 2; ++i)
        #pragma unroll
        for (int j = 0; j < 4; ++j)
            acc[i][j] = (f32x4){0.f, 0.f, 0.f, 0.f};

    const __hip_bfloat16* Ag = A + (size_t)(m0 + wave*16 + fr) * K + fq*8;
    int wr0 = n0 + wave*16 + fr; if (wr0 >= N) wr0 = N - 1;
    int wr1 = wr0 + 64;          if (wr1 >= N) wr1 = N - 1;
    const __hip_bfloat16* Wg0 = W + (size_t)wr0 * K + fq*8;
    const __hip_bfloat16* Wg1 = W + (size_t)wr1 * K + fq*8;

    for (int k0 = 0; k0 < K; k0 += 32) {
        gload_lds16(Ag  + k0, As + (size_t)wave*512);
        gload_lds16(Wg0 + k0, Bs + (size_t)wave*512);
        gload_lds16(Wg1 + k0, Bs + (size_t)(wave+4)*512);
        __syncthreads();
        bf16x8 af[2], bfr[4];
        #pragma unroll
        for (int i = 0; i < 2; ++i)
            af[i]  = *(const bf16x8*)(As + (size_t)(wm/16 + i)*512 + lane*8);
        #pragma unroll
        for (int j = 0; j < 4; ++j)
            bfr[j] = *(const bf16x8*)(Bs + (size_t)(wn/16 + j)*512 + lane*8);
        #pragma unroll
        for (int mi = 0; mi < 2; ++mi)
            #pragma unroll
            for (int ni = 0; ni < 4; ++ni)
                acc[mi][ni] = __builtin_amdgcn_mfma_f32_16x16x32_bf16(
                    af[mi], bfr[ni], acc[mi][ni], 0, 0, 0);
        __syncthreads();
    }

    #pragma unroll
    for (int ni = 0; ni < 4; ++ni) {
        int n = n0 + wn + ni*16 + fr;
        bool nok = n < N;
        float bv = (bias && nok) ? bias[n] : 0.f;
        #pragma unroll
        for (int mi = 0; mi < 2; ++mi) {
            #pragma unroll
            for (int r = 0; r < 4; ++r) {
                int m = m0 + wm + mi*16 + fq*4 + r;
                float v = acc[mi][ni][r] + bv;
                if (act) v = fmaxf(v, 0.f);
                if (nok) {
                    size_t idx = (size_t)m * N + n;
                    if (Cf) Cf[idx] = v;
                    if (Cb) Cb[idx] = __float2bfloat16(v);
                }
            }
        }
    }
}

// ---------------- fused scans + attention: 4 waves per (b,h) --------------
// 256 threads; thread owns e = tid (d_e=e>>2, p_e=e&3): fs, fk[8] for its e,
// and fv at (r = 2*p_e, 2*p_e+1; d = d_e). kdq/norm: wave butterfly + LDS
// cross-wave combine (1 barrier/iter, parity double-buffered). kv: 2 intra-
// wave shuffles over the 4 lanes sharing d. Depth-2 prefetch as before.
__global__ __launch_bounds__(256) void scan_attn_4w(
    const float* __restrict__ proj, const int* __restrict__ term,
    const float* __restrict__ tick, const float* __restrict__ tilde_k,
    const float* __restrict__ tilde_v, const float* __restrict__ s_prev,
    __hip_bfloat16* __restrict__ attn)
{
    const int b = blockIdx.x >> 3;
    const int h = blockIdx.x & 7;
    const int tid = threadIdx.x;
    const int w = tid >> 6, lane = tid & 63;
    const int e = tid, d_e = e >> 2, p_e = e & 3;
    const int rv0 = 2*p_e, rv1 = 2*p_e + 1;

    float fs = s_prev[((size_t)(b*HH + h))*256 + e];
    float fk[8];
    #pragma unroll
    for (int r = 0; r < 8; ++r)
        fk[r] = tilde_k[(((size_t)b*RR + r)*HH + h)*256 + e];
    float fv0 = tilde_v[(((size_t)b*RR + rv0)*HH + h)*64 + d_e];
    float fv1 = tilde_v[(((size_t)b*RR + rv1)*HH + h)*64 + d_e];

    const float PI_ = 3.14159265358979323846f;
    float tk = tick[b];
    float cw[8], sw[8], oc[8], os[8];
    #pragma unroll
    for (int r = 0; r < 8; ++r) {
        float wv = -PI_ + (float)r * (2.0f * PI_ / 7.0f);
        cw[r] = cosf(wv); sw[r] = sinf(wv);
        float a0 = (tk + 1.0f) * wv;
        oc[r] = cosf(a0); os[r] = sinf(a0);
    }
    // fv oscillators (same recurrence as oc[rv0]/oc[rv1], scalar indices)
    float wv0 = -PI_ + (float)rv0 * (2.0f * PI_ / 7.0f);
    float wv1 = -PI_ + (float)rv1 * (2.0f * PI_ / 7.0f);
    float cv0 = cosf(wv0), sv0 = sinf(wv0), cv1 = cosf(wv1), sv1 = sinf(wv1);
    float ocv0 = cosf((tk+1.0f)*wv0), osv0 = sinf((tk+1.0f)*wv0);
    float ocv1 = cosf((tk+1.0f)*wv1), osv1 = sinf((tk+1.0f)*wv1);

    __shared__ float red[2][4][12];

    struct PF { float k, q, v, bt, g, p1, p2, p3; int tm; };
    auto loadPF = [&](int t, PF& p) {
        if (t < TT) {
            const float* pn = proj + (size_t)(t*BBATCH + b) * NPROJ + h*320;
            p.k  = pn[d_e];
            p.q  = pn[64  + d_e];
            p.v  = pn[128 + d_e];
            p.bt = pn[192 + d_e];
            p.g  = pn[256 + d_e];
            const float* pe2 = proj + (size_t)(t*BBATCH + b) * NPROJ + KQV + h*12;
            p.p1 = pe2[p_e];
            p.p2 = pe2[4 + p_e];
            p.p3 = pe2[8 + p_e];
            p.tm = term[t*BBATCH + b];
        }
    };

    auto step = [&](int t, PF c) {
        float mask = 1.0f - (float)c.tm;
        float kr = fmaxf(c.k, 0.f);
        float qexp = fmaxf(c.q, 0.f) * fmaxf(c.p2, 0.f);
        float gexp = sigmoidf_(c.g) * sigmoidf_(c.p3);
        float kg = (kr * fmaxf(c.p1, 0.f)) * gexp;
        float dg = (1.f - gexp) * mask;

        fs = dg*fs + kg;
        float kdq[9];
        kdq[8] = fs * qexp;
        #pragma unroll
        for (int r = 0; r < 8; ++r) {
            fk[r] = dg*fk[r] + kg*oc[r];
            kdq[r] = fk[r] * qexp;
        }
        #pragma unroll
        for (int r = 0; r < 8; ++r) {
            float cc = oc[r], ss = os[r];
            oc[r] = cc*cw[r] - ss*sw[r];
            os[r] = ss*cw[r] + cc*sw[r];
        }
        // fv update (thread's two r's at d = d_e)
        float sb = sigmoidf_(c.bt);
        float vg = c.v * sb;
        float db = (1.f - sb) * mask;
        fv0 = db*fv0 + vg*ocv0;
        fv1 = db*fv1 + vg*ocv1;
        { float cc = ocv0, ss = osv0; ocv0 = cc*cv0 - ss*sv0; osv0 = ss*cv0 + cc*sv0; }
        { float cc = ocv1, ss = osv1; ocv1 = cc*cv1 - ss*sv1; osv1 = ss*cv1 + cc*sv1; }

        // wave-local allreduce of kdq[0..8]
        #pragma unroll
        for (int m = 1; m < 64; m <<= 1) {
            #pragma unroll
            for (int s2 = 0; s2 < 9; ++s2)
                kdq[s2] += __shfl_xor(kdq[s2], m);
        }
        int par = t & 1;
        if (lane == 0) {
            #pragma unroll
            for (int s2 = 0; s2 < 9; ++s2)
                red[par][w][s2] = kdq[s2];
        }
        __syncthreads();
        float kq0 = 0.f, kq1 = 0.f, nrm = 0.f;
        #pragma unroll
        for (int w2 = 0; w2 < 4; ++w2) {
            kq0 += red[par][w2][rv0];
            kq1 += red[par][w2][rv1];
            nrm += red[par][w2][8];
        }
        float kvp = fv0*kq0 + fv1*kq1;
        kvp += __shfl_xor(kvp, 1);
        kvp += __shfl_xor(kvp, 2);
        if (p_e == 0)
            attn[(size_t)(t*BBATCH + b)*DM + h*64 + d_e] =
                __float2bfloat16(kvp / (16.f * (nrm + 1e-6f)));
    };

    PF pf0, pf1;
    loadPF(0, pf0);
    loadPF(1, pf1);
    for (int t = 0; t < TT; t += 2) {
        PF c0 = pf0; loadPF(t + 2, pf0);
        step(t, c0);
        PF c1 = pf1; loadPF(t + 3, pf1);
        step(t + 1, c1);
    }
}

// ---------------- GRU elementwise phases ----------------------------------
__global__ __launch_bounds__(256) void gru_rz_kernel(const float* __restrict__ A1,
    const float* __restrict__ Bx, const float* __restrict__ x,
    __hip_bfloat16* __restrict__ rx, float* __restrict__ z)
{
    size_t i = (size_t)blockIdx.x * 256 + threadIdx.x;
    size_t m = i >> 9;
    int c = (int)(i & 511);
    float rpre = A1[m*1536 + c]       + Bx[m*1024 + c];
    float zpre = A1[m*1536 + 512 + c] + Bx[m*1024 + 512 + c] - 2.0f;
    rx[i] = __float2bfloat16(sigmoidf_(rpre) * x[i]);
    z[i]  = sigmoidf_(zpre);
}

// GRU2 final (writes d_out, f32)
__global__ __launch_bounds__(256) void gru_final_kernel(const float* __restrict__ A1,
    const float* __restrict__ C2, const float* __restrict__ z,
    const float* __restrict__ x, float* __restrict__ out)
{
    size_t i = (size_t)blockIdx.x * 256 + threadIdx.x;
    size_t m = i >> 9;
    int c = (int)(i & 511);
    float hh = tanhf(A1[m*1536 + 1024 + c] + C2[i]);
    float zz = z[i];
    out[i] = (1.0f - zz) * x[i] + zz * hh;
}

// GRU1 final fused with LN2: one block per row (256 thr, 2 elems each).
// Per-element math identical to gru_final; LN structure identical to ln_kernel.
__global__ __launch_bounds__(256) void gru_final_ln(
    const float* __restrict__ A1, const float* __restrict__ C2,
    const float* __restrict__ z, const float* __restrict__ x,
    const float* __restrict__ g, const float* __restrict__ bta,
    float* __restrict__ g1, __hip_bfloat16* __restrict__ g1b,
    __hip_bfloat16* __restrict__ fib)
{
    int row = blockIdx.x;
    int tid = threadIdx.x;
    size_t base = (size_t)row * DM;
    float2 c2v = ((const float2*)(C2 + base))[tid];
    float2 zv  = ((const float2*)(z  + base))[tid];
    float2 xv  = ((const float2*)(x  + base))[tid];
    float2 av  = ((const float2*)(A1 + (size_t)row*1536 + 1024))[tid];
    float h0 = tanhf(av.x + c2v.x);
    float h1 = tanhf(av.y + c2v.y);
    float2 v;
    v.x = (1.0f - zv.x) * xv.x + zv.x * h0;
    v.y = (1.0f - zv.y) * xv.y + zv.y * h1;
    ((float2*)(g1 + base))[tid] = v;
    g1b[base + 2*tid+0] = __float2bfloat16(v.x);
    g1b[base + 2*tid+1] = __float2bfloat16(v.y);

    float s = v.x + v.y;
    #pragma unroll
    for (int off = 32; off; off >>= 1) s += __shfl_down(s, off);
    __shared__ float red[8];
    int wid = tid >> 6, lane = tid & 63;
    if (lane == 0) red[wid] = s;
    __syncthreads();
    if (tid == 0) red[0] = (red[0] + red[1] + red[2] + red[3]) * (1.0f / DM);
    __syncthreads();
    float mean = red[0];
    float dx = v.x - mean, dy = v.y - mean;
    float sq = dx*dx + dy*dy;
    #pragma unroll
    for (int off = 32; off; off >>= 1) sq += __shfl_down(sq, off);
    if (lane == 0) red[4 + wid] = sq;
    __syncthreads();
    if (tid == 0) red[1] = rsqrtf((red[4]+red[5]+red[6]+red[7]) * (1.0f/DM) + 1e-5f);
    __syncthreads();
    float rstd = red[1];
    float2 gg = ((const float2*)g)[tid];
    float2 bb = ((const float2*)bta)[tid];
    fib[base + 2*tid+0] = __float2bfloat16(dx * rstd * gg.x + bb.x);
    fib[base + 2*tid+1] = __float2bfloat16(dy * rstd * gg.y + bb.y);
}

// ---------------- launch --------------------------------------------------
extern "C" void kernel_launch(void* const* d_in, const int* in_sizes, int n_in,
                              void* d_out, int out_size, void* d_ws, size_t ws_size,
                              hipStream_t stream)
{
    const float* inputs = (const float*)d_in[0];
    const int*   term   = (const int*)  d_in[1];
    const float* tilde_k= (const float*)d_in[2];
    const float* tilde_v= (const float*)d_in[3];
    const float* s_prev = (const float*)d_in[4];
    const float* tick   = (const float*)d_in[5];
    const float* w_proj = (const float*)d_in[6];
    const float* b_proj = (const float*)d_in[7];
    const float* w_attn = (const float*)d_in[8];
    const float* b_attn = (const float*)d_in[9];
    const float* ln1_g  = (const float*)d_in[10];
    const float* ln1_b  = (const float*)d_in[11];
    const float* ln2_g  = (const float*)d_in[12];
    const float* ln2_b  = (const float*)d_in[13];
    const float* gru1_w = (const float*)d_in[14];
    const float* gru1_u = (const float*)d_in[15];
    const float* gru2_w = (const float*)d_in[16];
    const float* gru2_u = (const float*)d_in[17];
    const float* ffc_w1 = (const float*)d_in[18];
    const float* ffc_b1 = (const float*)d_in[19];
    const float* ffc_w2 = (const float*)d_in[20];
    const float* ffc_b2 = (const float*)d_in[21];
    float* out = (float*)d_out;
    float* ws  = (float*)d_ws;

    // ---- f32 region (floats) ----
    float* proj = ws;                       // 4096x2656 (phase 1 only)
    float* A1   = ws;                       // 4096x1536 (overlays proj)
    float* Bx   = ws + 6291456;             // 4096x1024 (overlays proj tail)
    float* C2   = ws + 10878976;            // 4096x512
    float* zb   = ws + 12976128;            // 4096x512
    float* g1   = ws + 15073280;            // 4096x512
    // ---- bf16 region ----
    __hip_bfloat16* bb = (__hip_bfloat16*)(ws + 17170432);
    __hip_bfloat16* wp_bf  = bb + 0;          // 2656x512
    __hip_bfloat16* wat_bf = bb + 1359872;    // 512x512
    __hip_bfloat16* g1w_bf = bb + 1622016;    // 3x512x512
    __hip_bfloat16* g1u_bf = bb + 2408448;
    __hip_bfloat16* g2w_bf = bb + 3194880;
    __hip_bfloat16* g2u_bf = bb + 3981312;
    __hip_bfloat16* fw1_bf = bb + 4767744;    // 2048x512
    __hip_bfloat16* fw2_bf = bb + 5816320;    // 512x2048
    __hip_bfloat16* in_bf  = bb + 6864896;    // 4096x512
    __hip_bfloat16* xn_bf  = bb + 8962048;
    __hip_bfloat16* at_bf  = bb + 11059200;
    __hip_bfloat16* y1_bf  = bb + 13156352;
    __hip_bfloat16* rx_bf  = bb + 15253504;
    __hip_bfloat16* fi_bf  = bb + 17350656;
    __hip_bfloat16* mid_bf = bb + 19447808;   // 4096x2048
    __hip_bfloat16* fo_bf  = bb + 27836416;
    __hip_bfloat16* g1_bf  = bb + 29933568;

    dim3 blk(256);

    // 1. merged f32->bf16 conversions (one launch)
    F2B9 fa;
    const float* srcs[9] = {w_proj, w_attn, gru1_w, gru1_u, gru2_w, gru2_u,
                            ffc_w1, ffc_w2, inputs};
    __hip_bfloat16* dsts[9] = {wp_bf, wat_bf, g1w_bf, g1u_bf, g2w_bf, g2u_bf,
                               fw1_bf, fw2_bf, in_bf};
    int quads[9] = {339968, 65536, 196608, 196608, 196608, 196608,
                    262144, 262144, 524288};
    int cum = 0;
    for (int i = 0; i < 9; ++i) { fa.s[i] = srcs[i]; fa.d[i] = dsts[i]; fa.cum[i] = cum; cum += quads[i]; }
    fa.cum[9] = cum;   // 2,240,512 quads
    f2b_all<<<8752, blk, 0, stream>>>(fa);

    // 2. LN1 + projection
    ln_kernel<<<MM, blk, 0, stream>>>(inputs, ln1_g, ln1_b, xn_bf);
    gemm_bf16<<<dim3(21, 32), blk, 0, stream>>>(xn_bf, wp_bf, b_proj, proj, nullptr, NPROJ, DM, 0);

    // 3. fused scans + attention (4 waves per (b,h))
    scan_attn_4w<<<BBATCH*HH, blk, 0, stream>>>(proj, term, tick, tilde_k, tilde_v, s_prev, at_bf);

    // 4. attn out-proj (+relu), 64x128 tiles -> 256 blocks
    gemm_bf16_64<<<dim3(4, 64), blk, 0, stream>>>(at_bf, wat_bf, b_attn, nullptr, y1_bf, DM, DM, 1);

    // 5. GRU1: A1 = y1@[w0;w1;w2]^T and Bx = inputs@[u0;u1]^T in one launch
    gemm_bf16_dual<<<dim3(20, 32), blk, 0, stream>>>(y1_bf, g1w_bf, A1, 3*DM, 12,
                                                     in_bf, g1u_bf, Bx, 2*DM, DM);
    gru_rz_kernel<<<MM*DM/256, blk, 0, stream>>>(A1, Bx, inputs, rx_bf, zb);
    gemm_bf16_64<<<dim3(4, 64), blk, 0, stream>>>(rx_bf, g1u_bf + 2*DM*DM, nullptr, C2, nullptr, DM, DM, 0);
    gru_final_ln<<<MM, blk, 0, stream>>>(A1, C2, zb, inputs, ln2_g, ln2_b, g1, g1_bf, fi_bf);

    // 6. FFC
    gemm_bf16<<<dim3(16, 32), blk, 0, stream>>>(fi_bf, fw1_bf, ffc_b1, nullptr, mid_bf, 2048, DM, 1);
    gemm_bf16_64<<<dim3(4, 64), blk, 0, stream>>>(mid_bf, fw2_bf, ffc_b2, nullptr, fo_bf, DM, 2048, 1);

    // 7. GRU2: x = g1, y = ffout
    gemm_bf16_dual<<<dim3(20, 32), blk, 0, stream>>>(fo_bf, g2w_bf, A1, 3*DM, 12,
                                                     g1_bf, g2u_bf, Bx, 2*DM, DM);
    gru_rz_kernel<<<MM*DM/256, blk, 0, stream>>>(A1, Bx, g1, rx_bf, zb);
    gemm_bf16_64<<<dim3(4, 64), blk, 0, stream>>>(rx_bf, g2u_bf + 2*DM*DM, nullptr, C2, nullptr, DM, DM, 0);
    gru_final_kernel<<<MM*DM/256, blk, 0, stream>>>(A1, C2, zb, g1, out);
}

// Round 5
// 515.060 us; speedup vs baseline: 2.7819x; 1.0611x over previous
//
#include <hip/hip_runtime.h>
#include <hip/hip_bf16.h>
#include <math.h>

#define DM   512
#define HH   8
#define RR   8
#define TT   128
#define BBATCH 32
#define MM   (TT*BBATCH)     // 4096 rows
#define NPROJ 2656
#define KQV  2560

typedef __attribute__((ext_vector_type(8))) short bf16x8;
typedef __attribute__((ext_vector_type(4))) float f32x4;

__device__ __forceinline__ float sigmoidf_(float x) {
    return 1.0f / (1.0f + __expf(-x));
}

__device__ __forceinline__ void gload_lds16(const void* g, void* l) {
    __builtin_amdgcn_global_load_lds(
        (const __attribute__((address_space(1))) unsigned int*)g,
        (__attribute__((address_space(3))) unsigned int*)l, 16, 0, 0);
}

// ---------------- merged f32 -> bf16 conversions (9 segments, 1 launch) ---
struct F2B9 {
    const float* s[9];
    __hip_bfloat16* d[9];
    int cum[10];   // cumulative quad (float4) counts
};

__global__ __launch_bounds__(256) void f2b_all(F2B9 a)
{
    int q = blockIdx.x * 256 + threadIdx.x;
    if (q >= a.cum[9]) return;
    int s = 0;
    #pragma unroll
    for (int i = 1; i < 9; ++i) s += (q >= a.cum[i]);
    int i4 = (q - a.cum[s]) * 4;
    float4 v = *(const float4*)(a.s[s] + i4);
    __hip_bfloat16* dst = a.d[s] + i4;
    dst[0] = __float2bfloat16(v.x);
    dst[1] = __float2bfloat16(v.y);
    dst[2] = __float2bfloat16(v.z);
    dst[3] = __float2bfloat16(v.w);
}

// ---------------- LayerNorm -> bf16 out -----------------------------------
__global__ __launch_bounds__(256) void ln_kernel(const float* __restrict__ x,
    const float* __restrict__ g, const float* __restrict__ b,
    __hip_bfloat16* __restrict__ out)
{
    int row = blockIdx.x;
    int tid = threadIdx.x;
    const float* xr = x + (size_t)row * DM;
    float2 v = ((const float2*)xr)[tid];
    float s = v.x + v.y;
    #pragma unroll
    for (int off = 32; off; off >>= 1) s += __shfl_down(s, off);
    __shared__ float red[8];
    int wid = tid >> 6, lane = tid & 63;
    if (lane == 0) red[wid] = s;
    __syncthreads();
    if (tid == 0) red[0] = (red[0] + red[1] + red[2] + red[3]) * (1.0f / DM);
    __syncthreads();
    float mean = red[0];
    float dx = v.x - mean, dy = v.y - mean;
    float sq = dx*dx + dy*dy;
    #pragma unroll
    for (int off = 32; off; off >>= 1) sq += __shfl_down(sq, off);
    if (lane == 0) red[4 + wid] = sq;
    __syncthreads();
    if (tid == 0) red[1] = rsqrtf((red[4]+red[5]+red[6]+red[7]) * (1.0f/DM) + 1e-5f);
    __syncthreads();
    float rstd = red[1];
    float2 gg = ((const float2*)g)[tid];
    float2 bb = ((const float2*)b)[tid];
    __hip_bfloat16* orow = out + (size_t)row * DM;
    orow[2*tid+0] = __float2bfloat16(dx * rstd * gg.x + bb.x);
    orow[2*tid+1] = __float2bfloat16(dy * rstd * gg.y + bb.y);
}

// ---------------- bf16 MFMA GEMM core: 128x128 tile, BK=32 ----------------
__device__ __forceinline__ void gemm_core128(
    const __hip_bfloat16* __restrict__ A, const __hip_bfloat16* __restrict__ W,
    const float* __restrict__ bias,
    float* __restrict__ Cf, __hip_bfloat16* __restrict__ Cb,
    int N, int K, int act, int m0, int n0)
{
    __shared__ __attribute__((aligned(16))) __hip_bfloat16 As[8*512];
    __shared__ __attribute__((aligned(16))) __hip_bfloat16 Bs[8*512];
    int tid = threadIdx.x;
    int wave = tid >> 6, lane = tid & 63;
    int wm = (wave >> 1) * 64, wn = (wave & 1) * 64;
    int fr = lane & 15, fq = lane >> 4;

    f32x4 acc[4][4];
    #pragma unroll
    for (int i = 0; i < 4; ++i)
        #pragma unroll
        for (int j = 0; j < 4; ++j)
            acc[i][j] = (f32x4){0.f, 0.f, 0.f, 0.f};

    int sm0 = wave*16 + fr;
    int sm1 = sm0 + 64;
    int wr0 = n0 + sm0; if (wr0 >= N) wr0 = N - 1;
    int wr1 = n0 + sm1; if (wr1 >= N) wr1 = N - 1;
    const __hip_bfloat16* Ag0 = A + (size_t)(m0 + sm0) * K + fq*8;
    const __hip_bfloat16* Ag1 = A + (size_t)(m0 + sm1) * K + fq*8;
    const __hip_bfloat16* Wg0 = W + (size_t)wr0 * K + fq*8;
    const __hip_bfloat16* Wg1 = W + (size_t)wr1 * K + fq*8;

    for (int k0 = 0; k0 < K; k0 += 32) {
        gload_lds16(Ag0 + k0, As + (size_t)wave*512);
        gload_lds16(Ag1 + k0, As + (size_t)(wave+4)*512);
        gload_lds16(Wg0 + k0, Bs + (size_t)wave*512);
        gload_lds16(Wg1 + k0, Bs + (size_t)(wave+4)*512);
        __syncthreads();
        bf16x8 af[4], bfr[4];
        #pragma unroll
        for (int i = 0; i < 4; ++i) {
            af[i]  = *(const bf16x8*)(As + (size_t)(wm/16 + i)*512 + lane*8);
            bfr[i] = *(const bf16x8*)(Bs + (size_t)(wn/16 + i)*512 + lane*8);
        }
        #pragma unroll
        for (int mi = 0; mi < 4; ++mi)
            #pragma unroll
            for (int ni = 0; ni < 4; ++ni)
                acc[mi][ni] = __builtin_amdgcn_mfma_f32_16x16x32_bf16(
                    af[mi], bfr[ni], acc[mi][ni], 0, 0, 0);
        __syncthreads();
    }

    #pragma unroll
    for (int ni = 0; ni < 4; ++ni) {
        int n = n0 + wn + ni*16 + fr;
        bool nok = n < N;
        float bv = (bias && nok) ? bias[n] : 0.f;
        #pragma unroll
        for (int mi = 0; mi < 4; ++mi) {
            #pragma unroll
            for (int r = 0; r < 4; ++r) {
                int m = m0 + wm + mi*16 + fq*4 + r;
                float v = acc[mi][ni][r] + bv;
                if (act) v = fmaxf(v, 0.f);
                if (nok) {
                    size_t idx = (size_t)m * N + n;
                    if (Cf) Cf[idx] = v;
                    if (Cb) Cb[idx] = __float2bfloat16(v);
                }
            }
        }
    }
}

__global__ __launch_bounds__(256) void gemm_bf16(
    const __hip_bfloat16* __restrict__ A, const __hip_bfloat16* __restrict__ W,
    const float* __restrict__ bias,
    float* __restrict__ Cf, __hip_bfloat16* __restrict__ Cb,
    int N, int K, int act)
{
    gemm_core128(A, W, bias, Cf, Cb, N, K, act, blockIdx.y * 128, blockIdx.x * 128);
}

// dual-source GEMM: blocks [0,splitX) compute Ca = Aa@Wa^T, rest Cb2 = Ab@Wb^T
__global__ __launch_bounds__(256) void gemm_bf16_dual(
    const __hip_bfloat16* __restrict__ Aa, const __hip_bfloat16* __restrict__ Wa,
    float* __restrict__ Ca, int Na, int splitX,
    const __hip_bfloat16* __restrict__ Ab, const __hip_bfloat16* __restrict__ Wb,
    float* __restrict__ Cb2, int Nb, int K)
{
    int bx = blockIdx.x;
    if (bx < splitX)
        gemm_core128(Aa, Wa, nullptr, Ca, nullptr, Na, K, 0, blockIdx.y*128, bx*128);
    else
        gemm_core128(Ab, Wb, nullptr, Cb2, nullptr, Nb, K, 0, blockIdx.y*128, (bx-splitX)*128);
}

// ---------------- 64x128-tile GEMM (for N=512 cases: 256 blocks) ----------
__global__ __launch_bounds__(256) void gemm_bf16_64(
    const __hip_bfloat16* __restrict__ A, const __hip_bfloat16* __restrict__ W,
    const float* __restrict__ bias,
    float* __restrict__ Cf, __hip_bfloat16* __restrict__ Cb,
    int N, int K, int act)
{
    __shared__ __attribute__((aligned(16))) __hip_bfloat16 As[4*512];
    __shared__ __attribute__((aligned(16))) __hip_bfloat16 Bs[8*512];
    int tid = threadIdx.x;
    int wave = tid >> 6, lane = tid & 63;
    int m0 = blockIdx.y * 64, n0 = blockIdx.x * 128;
    int wm = (wave >> 1) * 32, wn = (wave & 1) * 64;
    int fr = lane & 15, fq = lane >> 4;

    f32x4 acc[2][4];
    #pragma unroll
    for (int i = 0; i < 2; ++i)
        #pragma unroll
        for (int j = 0; j < 4; ++j)
            acc[i][j] = (f32x4){0.f, 0.f, 0.f, 0.f};

    const __hip_bfloat16* Ag = A + (size_t)(m0 + wave*16 + fr) * K + fq*8;
    int wr0 = n0 + wave*16 + fr; if (wr0 >= N) wr0 = N - 1;
    int wr1 = wr0 + 64;          if (wr1 >= N) wr1 = N - 1;
    const __hip_bfloat16* Wg0 = W + (size_t)wr0 * K + fq*8;
    const __hip_bfloat16* Wg1 = W + (size_t)wr1 * K + fq*8;

    for (int k0 = 0; k0 < K; k0 += 32) {
        gload_lds16(Ag  + k0, As + (size_t)wave*512);
        gload_lds16(Wg0 + k0, Bs + (size_t)wave*512);
        gload_lds16(Wg1 + k0, Bs + (size_t)(wave+4)*512);
        __syncthreads();
        bf16x8 af[2], bfr[4];
        #pragma unroll
        for (int i = 0; i < 2; ++i)
            af[i]  = *(const bf16x8*)(As + (size_t)(wm/16 + i)*512 + lane*8);
        #pragma unroll
        for (int j = 0; j < 4; ++j)
            bfr[j] = *(const bf16x8*)(Bs + (size_t)(wn/16 + j)*512 + lane*8);
        #pragma unroll
        for (int mi = 0; mi < 2; ++mi)
            #pragma unroll
            for (int ni = 0; ni < 4; ++ni)
                acc[mi][ni] = __builtin_amdgcn_mfma_f32_16x16x32_bf16(
                    af[mi], bfr[ni], acc[mi][ni], 0, 0, 0);
        __syncthreads();
    }

    #pragma unroll
    for (int ni = 0; ni < 4; ++ni) {
        int n = n0 + wn + ni*16 + fr;
        bool nok = n < N;
        float bv = (bias && nok) ? bias[n] : 0.f;
        #pragma unroll
        for (int mi = 0; mi < 2; ++mi) {
            #pragma unroll
            for (int r = 0; r < 4; ++r) {
                int m = m0 + wm + mi*16 + fq*4 + r;
                float v = acc[mi][ni][r] + bv;
                if (act) v = fmaxf(v, 0.f);
                if (nok) {
                    size_t idx = (size_t)m * N + n;
                    if (Cf) Cf[idx] = v;
                    if (Cb) Cb[idx] = __float2bfloat16(v);
                }
            }
        }
    }
}

// ---------------- fused scans + attention: producer/consumer waves --------
// 2 waves per (b,h). Wave 1 streams proj slices into a 64-slot LDS ring
// (regular load -> ds_write, 4-t groups so loads pipeline); wave 0 runs the
// round-3 1-wave scan math reading from LDS. No __syncthreads in the loop
// (the per-iter barrier in r4 forced a vmcnt(0) drain = full load latency
// exposed 128x). Sync via workgroup-scope acquire/release on LDS counters.
#define NSLOT 64
#define SLOTF 384    // floats per slot (16B-aligned subfields)

__global__ __launch_bounds__(128) void scan_attn_pc(
    const float* __restrict__ proj, const int* __restrict__ term,
    const float* __restrict__ tick, const float* __restrict__ tilde_k,
    const float* __restrict__ tilde_v, const float* __restrict__ s_prev,
    __hip_bfloat16* __restrict__ attn)
{
    __shared__ __attribute__((aligned(16))) float slots[NSLOT * SLOTF]; // 96 KB
    __shared__ int prod_ctr, cons_ctr;

    const int b = blockIdx.x >> 3;
    const int h = blockIdx.x & 7;
    const int tid = threadIdx.x;
    const int wv = tid >> 6, lane = tid & 63;

    if (tid == 0) { prod_ctr = 0; cons_ctr = 0; }
    __syncthreads();   // init only

    if (wv == 1) {
        // ---------------- producer ----------------
        for (int t0 = 0; t0 < TT; t0 += 4) {
            if (t0 >= NSLOT) {
                int tgt = t0 - 56;
                while (__hip_atomic_load(&cons_ctr, __ATOMIC_ACQUIRE,
                                         __HIP_MEMORY_SCOPE_WORKGROUP) < tgt)
                    __builtin_amdgcn_s_sleep(8);
            }
            float va[4][5]; float pv[4];
            #pragma unroll
            for (int i = 0; i < 4; ++i) {
                const float* prow = proj + (size_t)((t0+i)*BBATCH + b) * NPROJ;
                const float* p5 = prow + h*320;
                va[i][0] = p5[lane];
                va[i][1] = p5[64  + lane];
                va[i][2] = p5[128 + lane];
                va[i][3] = p5[192 + lane];
                va[i][4] = p5[256 + lane];
                pv[i] = (lane < 12) ? prow[KQV + h*12 + lane] : 0.f;
            }
            #pragma unroll
            for (int i = 0; i < 4; ++i) {
                float* sl = slots + (size_t)((t0+i) & (NSLOT-1)) * SLOTF;
                sl[lane]       = va[i][0];
                sl[64  + lane] = va[i][1];
                sl[128 + lane] = va[i][2];
                sl[192 + lane] = va[i][3];
                sl[256 + lane] = va[i][4];
                if (lane < 12) sl[320 + lane] = pv[i];
            }
            if (lane == 0)
                __hip_atomic_store(&prod_ctr, t0 + 4, __ATOMIC_RELEASE,
                                   __HIP_MEMORY_SCOPE_WORKGROUP);
        }
        return;
    }

    // ---------------- consumer (round-3 math, inputs from LDS) ----------
    float4 fs = *(const float4*)(s_prev + ((size_t)(b*HH + h))*256 + lane*4);
    float4 fk[8];
    #pragma unroll
    for (int r = 0; r < 8; ++r)
        fk[r] = *(const float4*)(tilde_k + (((size_t)b*RR + r)*HH + h)*256 + lane*4);
    float fv[8];
    #pragma unroll
    for (int r = 0; r < 8; ++r)
        fv[r] = tilde_v[(((size_t)b*RR + r)*HH + h)*64 + lane];

    const float PI_ = 3.14159265358979323846f;
    float tk = tick[b];
    float cw[8], sw[8], oc[8], os[8];
    #pragma unroll
    for (int r = 0; r < 8; ++r) {
        float w = -PI_ + (float)r * (2.0f * PI_ / 7.0f);
        cw[r] = cosf(w); sw[r] = sinf(w);
        float a0 = (tk + 1.0f) * w;
        oc[r] = cosf(a0); os[r] = sinf(a0);
    }

    // preload all terminations for this b (t = lane and t = 64+lane)
    int ta  = term[lane*BBATCH + b];
    int tb_ = term[(64 + lane)*BBATCH + b];

    struct PF { float k, q, v, bt, g; float4 p1, p2, p3; };
    auto loadPF = [&](int t, PF& p) {
        if (t < TT) {
            const float* sl = slots + (size_t)(t & (NSLOT-1)) * SLOTF;
            p.k  = sl[lane];
            p.q  = sl[64  + lane];
            p.v  = sl[128 + lane];
            p.bt = sl[192 + lane];
            p.g  = sl[256 + lane];
            p.p1 = *(const float4*)(sl + 320);
            p.p2 = *(const float4*)(sl + 324);
            p.p3 = *(const float4*)(sl + 328);
        }
    };

    auto step = [&](int t, PF c) {
        int tm = (t < 64) ? __shfl(ta, t, 64) : __shfl(tb_, t - 64, 64);
        float mask = 1.0f - (float)tm;
        float kr = fmaxf(c.k, 0.f);
        float qr = fmaxf(c.q, 0.f);
        float sg = sigmoidf_(c.g);
        float p1a[4] = {c.p1.x, c.p1.y, c.p1.z, c.p1.w};
        float p2a[4] = {c.p2.x, c.p2.y, c.p2.z, c.p2.w};
        float p3a[4] = {c.p3.x, c.p3.y, c.p3.z, c.p3.w};
        float qexp[4], kg[4], dg[4];
        #pragma unroll
        for (int j = 0; j < 4; ++j) {
            float kexp = kr * fmaxf(p1a[j], 0.f);
            qexp[j]    = qr * fmaxf(p2a[j], 0.f);
            float gexp = sg * sigmoidf_(p3a[j]);
            kg[j] = kexp * gexp;
            dg[j] = (1.f - gexp) * mask;
        }
        fs.x = dg[0]*fs.x + kg[0];
        fs.y = dg[1]*fs.y + kg[1];
        fs.z = dg[2]*fs.z + kg[2];
        fs.w = dg[3]*fs.w + kg[3];
        float snorm = fs.x*qexp[0] + fs.y*qexp[1] + fs.z*qexp[2] + fs.w*qexp[3];
        float kdq[8];
        #pragma unroll
        for (int r = 0; r < 8; ++r) {
            float4 f = fk[r];
            float o = oc[r];
            f.x = dg[0]*f.x + kg[0]*o;
            f.y = dg[1]*f.y + kg[1]*o;
            f.z = dg[2]*f.z + kg[2]*o;
            f.w = dg[3]*f.w + kg[3]*o;
            fk[r] = f;
            kdq[r] = f.x*qexp[0] + f.y*qexp[1] + f.z*qexp[2] + f.w*qexp[3];
        }
        float sb = sigmoidf_(c.bt);
        float vg = c.v * sb;
        float db = (1.f - sb) * mask;
        #pragma unroll
        for (int r = 0; r < 8; ++r)
            fv[r] = db * fv[r] + vg * oc[r];
        #pragma unroll
        for (int r = 0; r < 8; ++r) {
            float cc = oc[r], ss = os[r];
            oc[r] = cc*cw[r] - ss*sw[r];
            os[r] = ss*cw[r] + cc*sw[r];
        }
        #pragma unroll
        for (int m = 1; m < 64; m <<= 1) {
            snorm += __shfl_xor(snorm, m);
            #pragma unroll
            for (int r = 0; r < 8; ++r)
                kdq[r] += __shfl_xor(kdq[r], m);
        }
        float kv = 0.f;
        #pragma unroll
        for (int r = 0; r < 8; ++r)
            kv += fv[r] * kdq[r];
        attn[(size_t)(t*BBATCH + b)*DM + h*64 + lane] =
            __float2bfloat16(kv / (16.f * (snorm + 1e-6f)));
    };

    // initial: wait for first 8 slots, prefetch t=0,1
    while (__hip_atomic_load(&prod_ctr, __ATOMIC_ACQUIRE,
                             __HIP_MEMORY_SCOPE_WORKGROUP) < 8)
        __builtin_amdgcn_s_sleep(2);
    PF pf0, pf1;
    loadPF(0, pf0);
    loadPF(1, pf1);

    for (int t = 0; t < TT; t += 2) {
        if ((t & 3) == 0) {
            if ((t & 15) == 0 && t >= 16 && lane == 0)
                __hip_atomic_store(&cons_ctr, t, __ATOMIC_RELEASE,
                                   __HIP_MEMORY_SCOPE_WORKGROUP);
            int tgt = (t + 8 > TT) ? TT : t + 8;
            while (__hip_atomic_load(&prod_ctr, __ATOMIC_ACQUIRE,
                                     __HIP_MEMORY_SCOPE_WORKGROUP) < tgt)
                __builtin_amdgcn_s_sleep(2);
        }
        PF c0 = pf0; loadPF(t + 2, pf0);
        step(t, c0);
        PF c1 = pf1; loadPF(t + 3, pf1);
        step(t + 1, c1);
    }
}

// ---------------- GRU elementwise phases ----------------------------------
__global__ __launch_bounds__(256) void gru_rz_kernel(const float* __restrict__ A1,
    const float* __restrict__ Bx, const float* __restrict__ x,
    __hip_bfloat16* __restrict__ rx, float* __restrict__ z)
{
    size_t i = (size_t)blockIdx.x * 256 + threadIdx.x;
    size_t m = i >> 9;
    int c = (int)(i & 511);
    float rpre = A1[m*1536 + c]       + Bx[m*1024 + c];
    float zpre = A1[m*1536 + 512 + c] + Bx[m*1024 + 512 + c] - 2.0f;
    rx[i] = __float2bfloat16(sigmoidf_(rpre) * x[i]);
    z[i]  = sigmoidf_(zpre);
}

__global__ __launch_bounds__(256) void gru_final_kernel(const float* __restrict__ A1,
    const float* __restrict__ C2, const float* __restrict__ z,
    const float* __restrict__ x, float* __restrict__ out)
{
    size_t i = (size_t)blockIdx.x * 256 + threadIdx.x;
    size_t m = i >> 9;
    int c = (int)(i & 511);
    float hh = tanhf(A1[m*1536 + 1024 + c] + C2[i]);
    float zz = z[i];
    out[i] = (1.0f - zz) * x[i] + zz * hh;
}

// GRU1 final fused with LN2
__global__ __launch_bounds__(256) void gru_final_ln(
    const float* __restrict__ A1, const float* __restrict__ C2,
    const float* __restrict__ z, const float* __restrict__ x,
    const float* __restrict__ g, const float* __restrict__ bta,
    float* __restrict__ g1, __hip_bfloat16* __restrict__ g1b,
    __hip_bfloat16* __restrict__ fib)
{
    int row = blockIdx.x;
    int tid = threadIdx.x;
    size_t base = (size_t)row * DM;
    float2 c2v = ((const float2*)(C2 + base))[tid];
    float2 zv  = ((const float2*)(z  + base))[tid];
    float2 xv  = ((const float2*)(x  + base))[tid];
    float2 av  = ((const float2*)(A1 + (size_t)row*1536 + 1024))[tid];
    float h0 = tanhf(av.x + c2v.x);
    float h1 = tanhf(av.y + c2v.y);
    float2 v;
    v.x = (1.0f - zv.x) * xv.x + zv.x * h0;
    v.y = (1.0f - zv.y) * xv.y + zv.y * h1;
    ((float2*)(g1 + base))[tid] = v;
    g1b[base + 2*tid+0] = __float2bfloat16(v.x);
    g1b[base + 2*tid+1] = __float2bfloat16(v.y);

    float s = v.x + v.y;
    #pragma unroll
    for (int off = 32; off; off >>= 1) s += __shfl_down(s, off);
    __shared__ float red[8];
    int wid = tid >> 6, lane = tid & 63;
    if (lane == 0) red[wid] = s;
    __syncthreads();
    if (tid == 0) red[0] = (red[0] + red[1] + red[2] + red[3]) * (1.0f / DM);
    __syncthreads();
    float mean = red[0];
    float dx = v.x - mean, dy = v.y - mean;
    float sq = dx*dx + dy*dy;
    #pragma unroll
    for (int off = 32; off; off >>= 1) sq += __shfl_down(sq, off);
    if (lane == 0) red[4 + wid] = sq;
    __syncthreads();
    if (tid == 0) red[1] = rsqrtf((red[4]+red[5]+red[6]+red[7]) * (1.0f/DM) + 1e-5f);
    __syncthreads();
    float rstd = red[1];
    float2 gg = ((const float2*)g)[tid];
    float2 bb = ((const float2*)bta)[tid];
    fib[base + 2*tid+0] = __float2bfloat16(dx * rstd * gg.x + bb.x);
    fib[base + 2*tid+1] = __float2bfloat16(dy * rstd * gg.y + bb.y);
}

// ---------------- launch --------------------------------------------------
extern "C" void kernel_launch(void* const* d_in, const int* in_sizes, int n_in,
                              void* d_out, int out_size, void* d_ws, size_t ws_size,
                              hipStream_t stream)
{
    const float* inputs = (const float*)d_in[0];
    const int*   term   = (const int*)  d_in[1];
    const float* tilde_k= (const float*)d_in[2];
    const float* tilde_v= (const float*)d_in[3];
    const float* s_prev = (const float*)d_in[4];
    const float* tick   = (const float*)d_in[5];
    const float* w_proj = (const float*)d_in[6];
    const float* b_proj = (const float*)d_in[7];
    const float* w_attn = (const float*)d_in[8];
    const float* b_attn = (const float*)d_in[9];
    const float* ln1_g  = (const float*)d_in[10];
    const float* ln1_b  = (const float*)d_in[11];
    const float* ln2_g  = (const float*)d_in[12];
    const float* ln2_b  = (const float*)d_in[13];
    const float* gru1_w = (const float*)d_in[14];
    const float* gru1_u = (const float*)d_in[15];
    const float* gru2_w = (const float*)d_in[16];
    const float* gru2_u = (const float*)d_in[17];
    const float* ffc_w1 = (const float*)d_in[18];
    const float* ffc_b1 = (const float*)d_in[19];
    const float* ffc_w2 = (const float*)d_in[20];
    const float* ffc_b2 = (const float*)d_in[21];
    float* out = (float*)d_out;
    float* ws  = (float*)d_ws;

    // ---- f32 region (floats) ----
    float* proj = ws;                       // 4096x2656 (phase 1 only)
    float* A1   = ws;                       // 4096x1536 (overlays proj)
    float* Bx   = ws + 6291456;             // 4096x1024 (overlays proj tail)
    float* C2   = ws + 10878976;            // 4096x512
    float* zb   = ws + 12976128;            // 4096x512
    float* g1   = ws + 15073280;            // 4096x512
    // ---- bf16 region ----
    __hip_bfloat16* bb = (__hip_bfloat16*)(ws + 17170432);
    __hip_bfloat16* wp_bf  = bb + 0;          // 2656x512
    __hip_bfloat16* wat_bf = bb + 1359872;    // 512x512
    __hip_bfloat16* g1w_bf = bb + 1622016;    // 3x512x512
    __hip_bfloat16* g1u_bf = bb + 2408448;
    __hip_bfloat16* g2w_bf = bb + 3194880;
    __hip_bfloat16* g2u_bf = bb + 3981312;
    __hip_bfloat16* fw1_bf = bb + 4767744;    // 2048x512
    __hip_bfloat16* fw2_bf = bb + 5816320;    // 512x2048
    __hip_bfloat16* in_bf  = bb + 6864896;    // 4096x512
    __hip_bfloat16* xn_bf  = bb + 8962048;
    __hip_bfloat16* at_bf  = bb + 11059200;
    __hip_bfloat16* y1_bf  = bb + 13156352;
    __hip_bfloat16* rx_bf  = bb + 15253504;
    __hip_bfloat16* fi_bf  = bb + 17350656;
    __hip_bfloat16* mid_bf = bb + 19447808;   // 4096x2048
    __hip_bfloat16* fo_bf  = bb + 27836416;
    __hip_bfloat16* g1_bf  = bb + 29933568;

    dim3 blk(256);

    // 1. merged f32->bf16 conversions (one launch)
    F2B9 fa;
    const float* srcs[9] = {w_proj, w_attn, gru1_w, gru1_u, gru2_w, gru2_u,
                            ffc_w1, ffc_w2, inputs};
    __hip_bfloat16* dsts[9] = {wp_bf, wat_bf, g1w_bf, g1u_bf, g2w_bf, g2u_bf,
                               fw1_bf, fw2_bf, in_bf};
    int quads[9] = {339968, 65536, 196608, 196608, 196608, 196608,
                    262144, 262144, 524288};
    int cum = 0;
    for (int i = 0; i < 9; ++i) { fa.s[i] = srcs[i]; fa.d[i] = dsts[i]; fa.cum[i] = cum; cum += quads[i]; }
    fa.cum[9] = cum;
    f2b_all<<<8752, blk, 0, stream>>>(fa);

    // 2. LN1 + projection
    ln_kernel<<<MM, blk, 0, stream>>>(inputs, ln1_g, ln1_b, xn_bf);
    gemm_bf16<<<dim3(21, 32), blk, 0, stream>>>(xn_bf, wp_bf, b_proj, proj, nullptr, NPROJ, DM, 0);

    // 3. fused scans + attention (producer/consumer wave pair per (b,h))
    scan_attn_pc<<<BBATCH*HH, dim3(128), 0, stream>>>(proj, term, tick, tilde_k, tilde_v, s_prev, at_bf);

    // 4. attn out-proj (+relu), 64x128 tiles -> 256 blocks
    gemm_bf16_64<<<dim3(4, 64), blk, 0, stream>>>(at_bf, wat_bf, b_attn, nullptr, y1_bf, DM, DM, 1);

    // 5. GRU1
    gemm_bf16_dual<<<dim3(20, 32), blk, 0, stream>>>(y1_bf, g1w_bf, A1, 3*DM, 12,
                                                     in_bf, g1u_bf, Bx, 2*DM, DM);
    gru_rz_kernel<<<MM*DM/256, blk, 0, stream>>>(A1, Bx, inputs, rx_bf, zb);
    gemm_bf16_64<<<dim3(4, 64), blk, 0, stream>>>(rx_bf, g1u_bf + 2*DM*DM, nullptr, C2, nullptr, DM, DM, 0);
    gru_final_ln<<<MM, blk, 0, stream>>>(A1, C2, zb, inputs, ln2_g, ln2_b, g1, g1_bf, fi_bf);

    // 6. FFC
    gemm_bf16<<<dim3(16, 32), blk, 0, stream>>>(fi_bf, fw1_bf, ffc_b1, nullptr, mid_bf, 2048, DM, 1);
    gemm_bf16_64<<<dim3(4, 64), blk, 0, stream>>>(mid_bf, fw2_bf, ffc_b2, nullptr, fo_bf, DM, 2048, 1);

    // 7. GRU2
    gemm_bf16_dual<<<dim3(20, 32), blk, 0, stream>>>(fo_bf, g2w_bf, A1, 3*DM, 12,
                                                     g1_bf, g2u_bf, Bx, 2*DM, DM);
    gru_rz_kernel<<<MM*DM/256, blk, 0, stream>>>(A1, Bx, g1, rx_bf, zb);
    gemm_bf16_64<<<dim3(4, 64), blk, 0, stream>>>(rx_bf, g2u_bf + 2*DM*DM, nullptr, C2, nullptr, DM, DM, 0);
    gru_final_kernel<<<MM*DM/256, blk, 0, stream>>>(A1, C2, zb, g1, out);
}

// Round 7
// 492.797 us; speedup vs baseline: 2.9075x; 1.0452x over previous
//
#include <hip/hip_runtime.h>
#include <hip/hip_bf16.h>
#include <math.h>

#define DM   512
#define HH   8
#define RR   8
#define TT   128
#define BBATCH 32
#define MM   (TT*BBATCH)     // 4096 rows
#define NPROJ 2656
#define KQV  2560

typedef __attribute__((ext_vector_type(8))) short bf16x8;
typedef __attribute__((ext_vector_type(4))) float f32x4;

__device__ __forceinline__ float sigmoidf_(float x) {
    return 1.0f / (1.0f + __expf(-x));
}

__device__ __forceinline__ void gload_lds16(const void* g, void* l) {
    __builtin_amdgcn_global_load_lds(
        (const __attribute__((address_space(1))) unsigned int*)g,
        (__attribute__((address_space(3))) unsigned int*)l, 16, 0, 0);
}

// ---- DPP wave64 sum -> uniform value --------------------------------------
template<int CTRL, int RMASK>
__device__ __forceinline__ float dpp_add_(float x) {
    union { float f; int i; } a, b;
    a.f = x;
    b.i = __builtin_amdgcn_update_dpp(0, a.i, CTRL, RMASK, 0xf, true);
    return x + b.f;
}
__device__ __forceinline__ float wave_sum_u(float x) {
    x = dpp_add_<0x111, 0xf>(x);   // row_shr:1
    x = dpp_add_<0x112, 0xf>(x);   // row_shr:2
    x = dpp_add_<0x114, 0xf>(x);   // row_shr:4
    x = dpp_add_<0x118, 0xf>(x);   // row_shr:8
    x = dpp_add_<0x142, 0xa>(x);   // row_bcast:15 -> rows 1,3
    x = dpp_add_<0x143, 0xc>(x);   // row_bcast:31 -> rows 2,3
    union { float f; int i; } s, t;
    s.f = x;
    t.i = __builtin_amdgcn_readlane(s.i, 63);
    return t.f;
}

// ---------------- merged f32 -> bf16 conversions (9 segments, 1 launch) ---
struct F2B9 {
    const float* s[9];
    __hip_bfloat16* d[9];
    int cum[10];
};

__global__ __launch_bounds__(256) void f2b_all(F2B9 a)
{
    int q = blockIdx.x * 256 + threadIdx.x;
    if (q >= a.cum[9]) return;
    int s = 0;
    #pragma unroll
    for (int i = 1; i < 9; ++i) s += (q >= a.cum[i]);
    int i4 = (q - a.cum[s]) * 4;
    float4 v = *(const float4*)(a.s[s] + i4);
    __hip_bfloat16* dst = a.d[s] + i4;
    dst[0] = __float2bfloat16(v.x);
    dst[1] = __float2bfloat16(v.y);
    dst[2] = __float2bfloat16(v.z);
    dst[3] = __float2bfloat16(v.w);
}

// ---------------- LayerNorm -> bf16 out -----------------------------------
__global__ __launch_bounds__(256) void ln_kernel(const float* __restrict__ x,
    const float* __restrict__ g, const float* __restrict__ b,
    __hip_bfloat16* __restrict__ out)
{
    int row = blockIdx.x;
    int tid = threadIdx.x;
    const float* xr = x + (size_t)row * DM;
    float2 v = ((const float2*)xr)[tid];
    float s = v.x + v.y;
    #pragma unroll
    for (int off = 32; off; off >>= 1) s += __shfl_down(s, off);
    __shared__ float red[8];
    int wid = tid >> 6, lane = tid & 63;
    if (lane == 0) red[wid] = s;
    __syncthreads();
    if (tid == 0) red[0] = (red[0] + red[1] + red[2] + red[3]) * (1.0f / DM);
    __syncthreads();
    float mean = red[0];
    float dx = v.x - mean, dy = v.y - mean;
    float sq = dx*dx + dy*dy;
    #pragma unroll
    for (int off = 32; off; off >>= 1) sq += __shfl_down(sq, off);
    if (lane == 0) red[4 + wid] = sq;
    __syncthreads();
    if (tid == 0) red[1] = rsqrtf((red[4]+red[5]+red[6]+red[7]) * (1.0f/DM) + 1e-5f);
    __syncthreads();
    float rstd = red[1];
    float2 gg = ((const float2*)g)[tid];
    float2 bb = ((const float2*)b)[tid];
    __hip_bfloat16* orow = out + (size_t)row * DM;
    orow[2*tid+0] = __float2bfloat16(dx * rstd * gg.x + bb.x);
    orow[2*tid+1] = __float2bfloat16(dy * rstd * gg.y + bb.y);
}

// ---------------- bf16 MFMA GEMM core: 128x128 tile, BK=32 ----------------
__device__ __forceinline__ void gemm_core128(
    const __hip_bfloat16* __restrict__ A, const __hip_bfloat16* __restrict__ W,
    const float* __restrict__ bias,
    float* __restrict__ Cf, __hip_bfloat16* __restrict__ Cb,
    int N, int K, int act, int m0, int n0)
{
    __shared__ __attribute__((aligned(16))) __hip_bfloat16 As[8*512];
    __shared__ __attribute__((aligned(16))) __hip_bfloat16 Bs[8*512];
    int tid = threadIdx.x;
    int wave = tid >> 6, lane = tid & 63;
    int wm = (wave >> 1) * 64, wn = (wave & 1) * 64;
    int fr = lane & 15, fq = lane >> 4;

    f32x4 acc[4][4];
    #pragma unroll
    for (int i = 0; i < 4; ++i)
        #pragma unroll
        for (int j = 0; j < 4; ++j)
            acc[i][j] = (f32x4){0.f, 0.f, 0.f, 0.f};

    int sm0 = wave*16 + fr;
    int sm1 = sm0 + 64;
    int wr0 = n0 + sm0; if (wr0 >= N) wr0 = N - 1;
    int wr1 = n0 + sm1; if (wr1 >= N) wr1 = N - 1;
    const __hip_bfloat16* Ag0 = A + (size_t)(m0 + sm0) * K + fq*8;
    const __hip_bfloat16* Ag1 = A + (size_t)(m0 + sm1) * K + fq*8;
    const __hip_bfloat16* Wg0 = W + (size_t)wr0 * K + fq*8;
    const __hip_bfloat16* Wg1 = W + (size_t)wr1 * K + fq*8;

    for (int k0 = 0; k0 < K; k0 += 32) {
        gload_lds16(Ag0 + k0, As + (size_t)wave*512);
        gload_lds16(Ag1 + k0, As + (size_t)(wave+4)*512);
        gload_lds16(Wg0 + k0, Bs + (size_t)wave*512);
        gload_lds16(Wg1 + k0, Bs + (size_t)(wave+4)*512);
        __syncthreads();
        bf16x8 af[4], bfr[4];
        #pragma unroll
        for (int i = 0; i < 4; ++i) {
            af[i]  = *(const bf16x8*)(As + (size_t)(wm/16 + i)*512 + lane*8);
            bfr[i] = *(const bf16x8*)(Bs + (size_t)(wn/16 + i)*512 + lane*8);
        }
        #pragma unroll
        for (int mi = 0; mi < 4; ++mi)
            #pragma unroll
            for (int ni = 0; ni < 4; ++ni)
                acc[mi][ni] = __builtin_amdgcn_mfma_f32_16x16x32_bf16(
                    af[mi], bfr[ni], acc[mi][ni], 0, 0, 0);
        __syncthreads();
    }

    #pragma unroll
    for (int ni = 0; ni < 4; ++ni) {
        int n = n0 + wn + ni*16 + fr;
        bool nok = n < N;
        float bv = (bias && nok) ? bias[n] : 0.f;
        #pragma unroll
        for (int mi = 0; mi < 4; ++mi) {
            #pragma unroll
            for (int r = 0; r < 4; ++r) {
                int m = m0 + wm + mi*16 + fq*4 + r;
                float v = acc[mi][ni][r] + bv;
                if (act) v = fmaxf(v, 0.f);
                if (nok) {
                    size_t idx = (size_t)m * N + n;
                    if (Cf) Cf[idx] = v;
                    if (Cb) Cb[idx] = __float2bfloat16(v);
                }
            }
        }
    }
}

__global__ __launch_bounds__(256) void gemm_bf16(
    const __hip_bfloat16* __restrict__ A, const __hip_bfloat16* __restrict__ W,
    const float* __restrict__ bias,
    float* __restrict__ Cf, __hip_bfloat16* __restrict__ Cb,
    int N, int K, int act)
{
    gemm_core128(A, W, bias, Cf, Cb, N, K, act, blockIdx.y * 128, blockIdx.x * 128);
}

// dual-source GEMM (GRU2): blocks [0,splitX) Ca = Aa@Wa^T, rest Cb2 = Ab@Wb^T
__global__ __launch_bounds__(256) void gemm_bf16_dual(
    const __hip_bfloat16* __restrict__ Aa, const __hip_bfloat16* __restrict__ Wa,
    float* __restrict__ Ca, int Na, int splitX,
    const __hip_bfloat16* __restrict__ Ab, const __hip_bfloat16* __restrict__ Wb,
    float* __restrict__ Cb2, int Nb, int K)
{
    int bx = blockIdx.x;
    if (bx < splitX)
        gemm_core128(Aa, Wa, nullptr, Ca, nullptr, Na, K, 0, blockIdx.y*128, bx*128);
    else
        gemm_core128(Ab, Wb, nullptr, Cb2, nullptr, Nb, K, 0, blockIdx.y*128, (bx-splitX)*128);
}

// ---------------- 64x128-tile GEMM (for N=512 cases: 256 blocks) ----------
__global__ __launch_bounds__(256) void gemm_bf16_64(
    const __hip_bfloat16* __restrict__ A, const __hip_bfloat16* __restrict__ W,
    const float* __restrict__ bias,
    float* __restrict__ Cf, __hip_bfloat16* __restrict__ Cb,
    int N, int K, int act)
{
    __shared__ __attribute__((aligned(16))) __hip_bfloat16 As[4*512];
    __shared__ __attribute__((aligned(16))) __hip_bfloat16 Bs[8*512];
    int tid = threadIdx.x;
    int wave = tid >> 6, lane = tid & 63;
    int m0 = blockIdx.y * 64, n0 = blockIdx.x * 128;
    int wm = (wave >> 1) * 32, wn = (wave & 1) * 64;
    int fr = lane & 15, fq = lane >> 4;

    f32x4 acc[2][4];
    #pragma unroll
    for (int i = 0; i < 2; ++i)
        #pragma unroll
        for (int j = 0; j < 4; ++j)
            acc[i][j] = (f32x4){0.f, 0.f, 0.f, 0.f};

    const __hip_bfloat16* Ag = A + (size_t)(m0 + wave*16 + fr) * K + fq*8;
    int wr0 = n0 + wave*16 + fr; if (wr0 >= N) wr0 = N - 1;
    int wr1 = wr0 + 64;          if (wr1 >= N) wr1 = N - 1;
    const __hip_bfloat16* Wg0 = W + (size_t)wr0 * K + fq*8;
    const __hip_bfloat16* Wg1 = W + (size_t)wr1 * K + fq*8;

    for (int k0 = 0; k0 < K; k0 += 32) {
        gload_lds16(Ag  + k0, As + (size_t)wave*512);
        gload_lds16(Wg0 + k0, Bs + (size_t)wave*512);
        gload_lds16(Wg1 + k0, Bs + (size_t)(wave+4)*512);
        __syncthreads();
        bf16x8 af[2], bfr[4];
        #pragma unroll
        for (int i = 0; i < 2; ++i)
            af[i]  = *(const bf16x8*)(As + (size_t)(wm/16 + i)*512 + lane*8);
        #pragma unroll
        for (int j = 0; j < 4; ++j)
            bfr[j] = *(const bf16x8*)(Bs + (size_t)(wn/16 + j)*512 + lane*8);
        #pragma unroll
        for (int mi = 0; mi < 2; ++mi)
            #pragma unroll
            for (int ni = 0; ni < 4; ++ni)
                acc[mi][ni] = __builtin_amdgcn_mfma_f32_16x16x32_bf16(
                    af[mi], bfr[ni], acc[mi][ni], 0, 0, 0);
        __syncthreads();
    }

    #pragma unroll
    for (int ni = 0; ni < 4; ++ni) {
        int n = n0 + wn + ni*16 + fr;
        bool nok = n < N;
        float bv = (bias && nok) ? bias[n] : 0.f;
        #pragma unroll
        for (int mi = 0; mi < 2; ++mi) {
            #pragma unroll
            for (int r = 0; r < 4; ++r) {
                int m = m0 + wm + mi*16 + fq*4 + r;
                float v = acc[mi][ni][r] + bv;
                if (act) v = fmaxf(v, 0.f);
                if (nok) {
                    size_t idx = (size_t)m * N + n;
                    if (Cf) Cf[idx] = v;
                    if (Cb) Cb[idx] = __float2bfloat16(v);
                }
            }
        }
    }
}

// ---------------- fused scans + attention + co-scheduled Bx GEMM ----------
// Blocks 0..255: producer/consumer scan per (b,h). Blocks 256..511: GRU1's
// Bx = inputs@[u0;u1]^T GEMM in the scan's occupancy shadow.
// NOTE: Bx MUST NOT overlap proj (r6 bug: Bx overlaid proj rows >=2369 and
// the co-scheduled GEMM clobbered them while the scan still read t>=74).
#define NSLOT 16
#define SLOTF 384

__global__ __launch_bounds__(256) void scan_attn_fused(
    const float* __restrict__ proj, const int* __restrict__ term,
    const float* __restrict__ tick, const float* __restrict__ tilde_k,
    const float* __restrict__ tilde_v, const float* __restrict__ s_prev,
    __hip_bfloat16* __restrict__ attn,
    const __hip_bfloat16* __restrict__ gA, const __hip_bfloat16* __restrict__ gW,
    float* __restrict__ gC)
{
    int bid = blockIdx.x;
    if (bid >= 256) {
        int g = bid - 256;
        gemm_core128(gA, gW, nullptr, gC, nullptr, 1024, DM, 0,
                     (g >> 3) * 128, (g & 7) * 128);
        return;
    }

    __shared__ __attribute__((aligned(16))) float slots[NSLOT * SLOTF]; // 24.5 KB
    __shared__ int prod_ctr, cons_ctr;

    const int b = bid >> 3;
    const int h = bid & 7;
    const int tid = threadIdx.x;
    const int wv = tid >> 6, lane = tid & 63;

    if (tid == 0) { prod_ctr = 0; cons_ctr = 0; }
    __syncthreads();   // init only (all 4 waves participate)
    if (wv >= 2) return;

    if (wv == 1) {
        // ---------------- producer ----------------
        for (int t0 = 0; t0 < TT; t0 += 4) {
            if (t0 >= NSLOT) {
                int tgt = t0 - 12;
                while (__hip_atomic_load(&cons_ctr, __ATOMIC_ACQUIRE,
                                         __HIP_MEMORY_SCOPE_WORKGROUP) < tgt)
                    __builtin_amdgcn_s_sleep(8);
            }
            float va[4][5]; float pv[4];
            #pragma unroll
            for (int i = 0; i < 4; ++i) {
                const float* prow = proj + (size_t)((t0+i)*BBATCH + b) * NPROJ;
                const float* p5 = prow + h*320;
                va[i][0] = p5[lane];
                va[i][1] = p5[64  + lane];
                va[i][2] = p5[128 + lane];
                va[i][3] = p5[192 + lane];
                va[i][4] = p5[256 + lane];
                pv[i] = (lane < 12) ? prow[KQV + h*12 + lane] : 0.f;
            }
            #pragma unroll
            for (int i = 0; i < 4; ++i) {
                float* sl = slots + (size_t)((t0+i) & (NSLOT-1)) * SLOTF;
                sl[lane]       = va[i][0];
                sl[64  + lane] = va[i][1];
                sl[128 + lane] = va[i][2];
                sl[192 + lane] = va[i][3];
                sl[256 + lane] = va[i][4];
                if (lane < 12) sl[320 + lane] = pv[i];
            }
            if (lane == 0)
                __hip_atomic_store(&prod_ctr, t0 + 4, __ATOMIC_RELEASE,
                                   __HIP_MEMORY_SCOPE_WORKGROUP);
        }
        return;
    }

    // ---------------- consumer ----------------
    float4 fs = *(const float4*)(s_prev + ((size_t)(b*HH + h))*256 + lane*4);
    float4 fk[8];
    #pragma unroll
    for (int r = 0; r < 8; ++r)
        fk[r] = *(const float4*)(tilde_k + (((size_t)b*RR + r)*HH + h)*256 + lane*4);
    float fv[8];
    #pragma unroll
    for (int r = 0; r < 8; ++r)
        fv[r] = tilde_v[(((size_t)b*RR + r)*HH + h)*64 + lane];

    const float PI_ = 3.14159265358979323846f;
    float tk = tick[b];
    float cw[8], sw[8], oc[8], os[8];
    #pragma unroll
    for (int r = 0; r < 8; ++r) {
        float w = -PI_ + (float)r * (2.0f * PI_ / 7.0f);
        cw[r] = cosf(w); sw[r] = sinf(w);
        float a0 = (tk + 1.0f) * w;
        oc[r] = cosf(a0); os[r] = sinf(a0);
    }

    // preload all terminations for this b: t = lane and t = 64+lane
    int ta  = term[lane*BBATCH + b];
    int tb_ = term[(64 + lane)*BBATCH + b];

    struct PF { float k, q, v, bt, g; float4 p1, p2, p3; };
    auto loadPF = [&](int t, PF& p) {
        if (t < TT) {
            const float* sl = slots + (size_t)(t & (NSLOT-1)) * SLOTF;
            p.k  = sl[lane];
            p.q  = sl[64  + lane];
            p.v  = sl[128 + lane];
            p.bt = sl[192 + lane];
            p.g  = sl[256 + lane];
            p.p1 = *(const float4*)(sl + 320);
            p.p2 = *(const float4*)(sl + 324);
            p.p3 = *(const float4*)(sl + 328);
        }
    };

    auto step = [&](int t, PF c) {
        int tm = (t < 64) ? __builtin_amdgcn_readlane(ta, t)
                          : __builtin_amdgcn_readlane(tb_, t - 64);
        float mask = 1.0f - (float)tm;
        float kr = fmaxf(c.k, 0.f);
        float qr = fmaxf(c.q, 0.f);
        float sg = sigmoidf_(c.g);
        float p1a[4] = {c.p1.x, c.p1.y, c.p1.z, c.p1.w};
        float p2a[4] = {c.p2.x, c.p2.y, c.p2.z, c.p2.w};
        float p3a[4] = {c.p3.x, c.p3.y, c.p3.z, c.p3.w};
        float qexp[4], kg[4], dg[4];
        #pragma unroll
        for (int j = 0; j < 4; ++j) {
            float kexp = kr * fmaxf(p1a[j], 0.f);
            qexp[j]    = qr * fmaxf(p2a[j], 0.f);
            float gexp = sg * sigmoidf_(p3a[j]);
            kg[j] = kexp * gexp;
            dg[j] = (1.f - gexp) * mask;
        }
        fs.x = dg[0]*fs.x + kg[0];
        fs.y = dg[1]*fs.y + kg[1];
        fs.z = dg[2]*fs.z + kg[2];
        fs.w = dg[3]*fs.w + kg[3];
        float snorm = fs.x*qexp[0] + fs.y*qexp[1] + fs.z*qexp[2] + fs.w*qexp[3];
        float kdq[8];
        #pragma unroll
        for (int r = 0; r < 8; ++r) {
            float4 f = fk[r];
            float o = oc[r];
            f.x = dg[0]*f.x + kg[0]*o;
            f.y = dg[1]*f.y + kg[1]*o;
            f.z = dg[2]*f.z + kg[2]*o;
            f.w = dg[3]*f.w + kg[3]*o;
            fk[r] = f;
            kdq[r] = f.x*qexp[0] + f.y*qexp[1] + f.z*qexp[2] + f.w*qexp[3];
        }
        float sb = sigmoidf_(c.bt);
        float vg = c.v * sb;
        float db = (1.f - sb) * mask;
        #pragma unroll
        for (int r = 0; r < 8; ++r)
            fv[r] = db * fv[r] + vg * oc[r];
        #pragma unroll
        for (int r = 0; r < 8; ++r) {
            float cc = oc[r], ss = os[r];
            oc[r] = cc*cw[r] - ss*sw[r];
            os[r] = ss*cw[r] + cc*sw[r];
        }
        // DPP wave sums -> uniform values (pure VALU, no LDS-pipe shuffles)
        float nrm_u = wave_sum_u(snorm);
        float kdq_u[8];
        #pragma unroll
        for (int r = 0; r < 8; ++r)
            kdq_u[r] = wave_sum_u(kdq[r]);
        float kv = 0.f;
        #pragma unroll
        for (int r = 0; r < 8; ++r)
            kv += fv[r] * kdq_u[r];
        attn[(size_t)(t*BBATCH + b)*DM + h*64 + lane] =
            __float2bfloat16(kv / (16.f * (nrm_u + 1e-6f)));
    };

    while (__hip_atomic_load(&prod_ctr, __ATOMIC_ACQUIRE,
                             __HIP_MEMORY_SCOPE_WORKGROUP) < 8)
        __builtin_amdgcn_s_sleep(2);
    PF pf0, pf1;
    loadPF(0, pf0);
    loadPF(1, pf1);

    for (int t = 0; t < TT; t += 2) {
        if ((t & 3) == 0) {
            if ((t & 7) == 0 && t >= 8 && lane == 0)
                __hip_atomic_store(&cons_ctr, t - 2, __ATOMIC_RELEASE,
                                   __HIP_MEMORY_SCOPE_WORKGROUP);
            int tgt = (t + 8 > TT) ? TT : t + 8;
            while (__hip_atomic_load(&prod_ctr, __ATOMIC_ACQUIRE,
                                     __HIP_MEMORY_SCOPE_WORKGROUP) < tgt)
                __builtin_amdgcn_s_sleep(2);
        }
        PF c0 = pf0; loadPF(t + 2, pf0);
        step(t, c0);
        PF c1 = pf1; loadPF(t + 3, pf1);
        step(t + 1, c1);
    }
}

// ---------------- GRU elementwise phases ----------------------------------
__global__ __launch_bounds__(256) void gru_rz_kernel(const float* __restrict__ A1,
    const float* __restrict__ Bx, const float* __restrict__ x,
    __hip_bfloat16* __restrict__ rx, float* __restrict__ z)
{
    size_t i = (size_t)blockIdx.x * 256 + threadIdx.x;
    size_t m = i >> 9;
    int c = (int)(i & 511);
    float rpre = A1[m*1536 + c]       + Bx[m*1024 + c];
    float zpre = A1[m*1536 + 512 + c] + Bx[m*1024 + 512 + c] - 2.0f;
    rx[i] = __float2bfloat16(sigmoidf_(rpre) * x[i]);
    z[i]  = sigmoidf_(zpre);
}

__global__ __launch_bounds__(256) void gru_final_kernel(const float* __restrict__ A1,
    const float* __restrict__ C2, const float* __restrict__ z,
    const float* __restrict__ x, float* __restrict__ out)
{
    size_t i = (size_t)blockIdx.x * 256 + threadIdx.x;
    size_t m = i >> 9;
    int c = (int)(i & 511);
    float hh = tanhf(A1[m*1536 + 1024 + c] + C2[i]);
    float zz = z[i];
    out[i] = (1.0f - zz) * x[i] + zz * hh;
}

// GRU1 final fused with LN2
__global__ __launch_bounds__(256) void gru_final_ln(
    const float* __restrict__ A1, const float* __restrict__ C2,
    const float* __restrict__ z, const float* __restrict__ x,
    const float* __restrict__ g, const float* __restrict__ bta,
    float* __restrict__ g1, __hip_bfloat16* __restrict__ g1b,
    __hip_bfloat16* __restrict__ fib)
{
    int row = blockIdx.x;
    int tid = threadIdx.x;
    size_t base = (size_t)row * DM;
    float2 c2v = ((const float2*)(C2 + base))[tid];
    float2 zv  = ((const float2*)(z  + base))[tid];
    float2 xv  = ((const float2*)(x  + base))[tid];
    float2 av  = ((const float2*)(A1 + (size_t)row*1536 + 1024))[tid];
    float h0 = tanhf(av.x + c2v.x);
    float h1 = tanhf(av.y + c2v.y);
    float2 v;
    v.x = (1.0f - zv.x) * xv.x + zv.x * h0;
    v.y = (1.0f - zv.y) * xv.y + zv.y * h1;
    ((float2*)(g1 + base))[tid] = v;
    g1b[base + 2*tid+0] = __float2bfloat16(v.x);
    g1b[base + 2*tid+1] = __float2bfloat16(v.y);

    float s = v.x + v.y;
    #pragma unroll
    for (int off = 32; off; off >>= 1) s += __shfl_down(s, off);
    __shared__ float red[8];
    int wid = tid >> 6, lane = tid & 63;
    if (lane == 0) red[wid] = s;
    __syncthreads();
    if (tid == 0) red[0] = (red[0] + red[1] + red[2] + red[3]) * (1.0f / DM);
    __syncthreads();
    float mean = red[0];
    float dx = v.x - mean, dy = v.y - mean;
    float sq = dx*dx + dy*dy;
    #pragma unroll
    for (int off = 32; off; off >>= 1) sq += __shfl_down(sq, off);
    if (lane == 0) red[4 + wid] = sq;
    __syncthreads();
    if (tid == 0) red[1] = rsqrtf((red[4]+red[5]+red[6]+red[7]) * (1.0f/DM) + 1e-5f);
    __syncthreads();
    float rstd = red[1];
    float2 gg = ((const float2*)g)[tid];
    float2 bb = ((const float2*)bta)[tid];
    fib[base + 2*tid+0] = __float2bfloat16(dx * rstd * gg.x + bb.x);
    fib[base + 2*tid+1] = __float2bfloat16(dy * rstd * gg.y + bb.y);
}

// ---------------- launch --------------------------------------------------
extern "C" void kernel_launch(void* const* d_in, const int* in_sizes, int n_in,
                              void* d_out, int out_size, void* d_ws, size_t ws_size,
                              hipStream_t stream)
{
    const float* inputs = (const float*)d_in[0];
    const int*   term   = (const int*)  d_in[1];
    const float* tilde_k= (const float*)d_in[2];
    const float* tilde_v= (const float*)d_in[3];
    const float* s_prev = (const float*)d_in[4];
    const float* tick   = (const float*)d_in[5];
    const float* w_proj = (const float*)d_in[6];
    const float* b_proj = (const float*)d_in[7];
    const float* w_attn = (const float*)d_in[8];
    const float* b_attn = (const float*)d_in[9];
    const float* ln1_g  = (const float*)d_in[10];
    const float* ln1_b  = (const float*)d_in[11];
    const float* ln2_g  = (const float*)d_in[12];
    const float* ln2_b  = (const float*)d_in[13];
    const float* gru1_w = (const float*)d_in[14];
    const float* gru1_u = (const float*)d_in[15];
    const float* gru2_w = (const float*)d_in[16];
    const float* gru2_u = (const float*)d_in[17];
    const float* ffc_w1 = (const float*)d_in[18];
    const float* ffc_b1 = (const float*)d_in[19];
    const float* ffc_w2 = (const float*)d_in[20];
    const float* ffc_b2 = (const float*)d_in[21];
    float* out = (float*)d_out;
    float* ws  = (float*)d_ws;

    // ---- f32 region (floats) ----
    float* proj = ws;                       // 4096x2656 (phase 1 only)
    float* A1   = ws;                       // 4096x1536 (overlays proj; written AFTER scan)
    float* C2   = ws + 10878976;            // 4096x512
    float* zb   = ws + 12976128;            // 4096x512
    float* g1   = ws + 15073280;            // 4096x512
    // ---- bf16 region ----
    __hip_bfloat16* bb = (__hip_bfloat16*)(ws + 17170432);
    __hip_bfloat16* wp_bf  = bb + 0;          // 2656x512
    __hip_bfloat16* wat_bf = bb + 1359872;    // 512x512
    __hip_bfloat16* g1w_bf = bb + 1622016;    // 3x512x512
    __hip_bfloat16* g1u_bf = bb + 2408448;
    __hip_bfloat16* g2w_bf = bb + 3194880;
    __hip_bfloat16* g2u_bf = bb + 3981312;
    __hip_bfloat16* fw1_bf = bb + 4767744;    // 2048x512
    __hip_bfloat16* fw2_bf = bb + 5816320;    // 512x2048
    __hip_bfloat16* in_bf  = bb + 6864896;    // 4096x512
    __hip_bfloat16* xn_bf  = bb + 8962048;
    __hip_bfloat16* at_bf  = bb + 11059200;
    __hip_bfloat16* y1_bf  = bb + 13156352;
    __hip_bfloat16* rx_bf  = bb + 15253504;
    __hip_bfloat16* fi_bf  = bb + 17350656;
    __hip_bfloat16* mid_bf = bb + 19447808;   // 4096x2048
    __hip_bfloat16* fo_bf  = bb + 27836416;
    __hip_bfloat16* g1_bf  = bb + 29933568;
    // Bx AFTER bf16 region — must NOT overlap proj (r6 race): float offset
    // 17170432 + 32030720/2 = 33185792; 4096x1024 floats -> total ~149.5 MB.
    float* Bx = ws + 33185792;

    dim3 blk(256);

    // 1. merged f32->bf16 conversions (one launch)
    F2B9 fa;
    const float* srcs[9] = {w_proj, w_attn, gru1_w, gru1_u, gru2_w, gru2_u,
                            ffc_w1, ffc_w2, inputs};
    __hip_bfloat16* dsts[9] = {wp_bf, wat_bf, g1w_bf, g1u_bf, g2w_bf, g2u_bf,
                               fw1_bf, fw2_bf, in_bf};
    int quads[9] = {339968, 65536, 196608, 196608, 196608, 196608,
                    262144, 262144, 524288};
    int cum = 0;
    for (int i = 0; i < 9; ++i) { fa.s[i] = srcs[i]; fa.d[i] = dsts[i]; fa.cum[i] = cum; cum += quads[i]; }
    fa.cum[9] = cum;
    f2b_all<<<8752, blk, 0, stream>>>(fa);

    // 2. LN1 + projection
    ln_kernel<<<MM, blk, 0, stream>>>(inputs, ln1_g, ln1_b, xn_bf);
    gemm_bf16<<<dim3(21, 32), blk, 0, stream>>>(xn_bf, wp_bf, b_proj, proj, nullptr, NPROJ, DM, 0);

    // 3. fused scans + attention, with GRU1's Bx GEMM co-scheduled
    scan_attn_fused<<<512, blk, 0, stream>>>(proj, term, tick, tilde_k, tilde_v,
                                             s_prev, at_bf, in_bf, g1u_bf, Bx);

    // 4. attn out-proj (+relu)
    gemm_bf16_64<<<dim3(4, 64), blk, 0, stream>>>(at_bf, wat_bf, b_attn, nullptr, y1_bf, DM, DM, 1);

    // 5. GRU1 (Bx already computed inside scan dispatch)
    gemm_bf16<<<dim3(12, 32), blk, 0, stream>>>(y1_bf, g1w_bf, nullptr, A1, nullptr, 3*DM, DM, 0);
    gru_rz_kernel<<<MM*DM/256, blk, 0, stream>>>(A1, Bx, inputs, rx_bf, zb);
    gemm_bf16_64<<<dim3(4, 64), blk, 0, stream>>>(rx_bf, g1u_bf + 2*DM*DM, nullptr, C2, nullptr, DM, DM, 0);
    gru_final_ln<<<MM, blk, 0, stream>>>(A1, C2, zb, inputs, ln2_g, ln2_b, g1, g1_bf, fi_bf);

    // 6. FFC
    gemm_bf16<<<dim3(16, 32), blk, 0, stream>>>(fi_bf, fw1_bf, ffc_b1, nullptr, mid_bf, 2048, DM, 1);
    gemm_bf16_64<<<dim3(4, 64), blk, 0, stream>>>(mid_bf, fw2_bf, ffc_b2, nullptr, fo_bf, DM, 2048, 1);

    // 7. GRU2
    gemm_bf16_dual<<<dim3(20, 32), blk, 0, stream>>>(fo_bf, g2w_bf, A1, 3*DM, 12,
                                                     g1_bf, g2u_bf, Bx, 2*DM, DM);
    gru_rz_kernel<<<MM*DM/256, blk, 0, stream>>>(A1, Bx, g1, rx_bf, zb);
    gemm_bf16_64<<<dim3(4, 64), blk, 0, stream>>>(rx_bf, g2u_bf + 2*DM*DM, nullptr, C2, nullptr, DM, DM, 0);
    gru_final_kernel<<<MM*DM/256, blk, 0, stream>>>(A1, C2, zb, g1, out);
}